// Round 3
// 216.505 us; speedup vs baseline: 1.0766x; 1.0766x over previous
//
#include <hip/hip_runtime.h>
#include <hip/hip_bf16.h>
#include <math.h>

// B=4, L=S=2048, H=8, E=64, T=1.0.  I/O fp32.
// Pipeline: tr_fwd (coalesced transpose [B,T,H,E]->bf16 [tensor,bh,e][t])
// -> fft_fwd (real-packed 1024-pt FFT, bf16 planes; Q plane pre-scaled 0.125;
//    V plane chunk-swizzled by (kk>>2)&3 for conflict-free PV ds_reads)
// -> qkpack (K chunks XOR-swizzled at source for linear-LDS DMA) -> flash_mfma
// (global_load_lds K/V staging, LDS dbuf, counted vmcnt(4), raw s_barrier,
//  setprio around MFMA, cvt_pk softmax/epilogue packing) -> fft_inv -> out_tr.
// R11: fix R9 NaN — GLD16 offset arg semantics ambiguous (may offset LDS addr
// on LDS-DMA); use offset=0 always with explicit global pointer arithmetic.
// Plus V chunk swizzle (kills 8-way PV bank conflict of linear Vs[128][32]).
#define LOGN  11
#define NN    2048
#define LOGM  10
#define MM    1024
#define NF    1025
#define NYP   1056         // NF padded to 33 tiles of 32 (pads zeroed)
#define TWO_PI 6.283185307179586f
#define INV_SQRT_N 0.022097086912079608f      // 1/sqrt(2048)
#define INV_SCALE  0.044194173824159216f      // 2/sqrt(2048)  (M*z -> out)

typedef __attribute__((ext_vector_type(8))) short bhalf8;
typedef __attribute__((ext_vector_type(4))) float f32x4;

#define MFMA16(a, b, c) __builtin_amdgcn_mfma_f32_16x16x32_bf16(a, b, c, 0, 0, 0)

#define GLD16(gp, lp)                                                              \
    __builtin_amdgcn_global_load_lds(                                              \
        (const __attribute__((address_space(1))) void*)(gp),                       \
        (__attribute__((address_space(3))) void*)(lp), 16, 0, 0)

#define CVTPK(dst, lo, hi) \
    asm("v_cvt_pk_bf16_f32 %0, %1, %2" : "=v"(dst) : "v"(lo), "v"(hi))

__device__ __forceinline__ unsigned short f2bf(float f) {
    union { float f; unsigned u; } v; v.f = f;
    unsigned r = v.u + 0x7FFFu + ((v.u >> 16) & 1u);   // RNE
    return (unsigned short)(r >> 16);
}
__device__ __forceinline__ float bf2f(unsigned short h) {
    union { unsigned u; float f; } v; v.u = ((unsigned)h) << 16;
    return v.f;
}

// ---------------------------------------------------------------------------
// 1024-pt complex DIT stages in LDS (input pre-bit-reversed).
// ---------------------------------------------------------------------------
__device__ __forceinline__ void fft_stages_m(float2* buf, const float2* tw, int tid)
{
    for (int st = 1; st <= LOGM; st++) {
        int half = 1 << (st - 1);
        #pragma unroll
        for (int it = 0; it < 2; it++) {
            int j   = tid + 256 * it;          // 512 butterflies
            int pos = j & (half - 1);
            int grp = j >> (st - 1);
            int i0  = (grp << st) + pos;
            int i1  = i0 + half;
            float2 w = tw[pos << (LOGM - st)];
            float2 a = buf[i0];
            float2 b = buf[i1];
            float2 bw = make_float2(b.x * w.x - b.y * w.y,
                                    b.x * w.y + b.y * w.x);
            buf[i0] = make_float2(a.x + bw.x, a.y + bw.y);
            buf[i1] = make_float2(a.x - bw.x, a.y - bw.y);
        }
        __syncthreads();
    }
}

// ---------------------------------------------------------------------------
// Input transpose: in[b][t][h][e] fp32 -> ttr[(tensor*32+bh)*64+e][t] bf16.
// 64x64 tiles via LDS; both global sides fully coalesced; packed u32x2 stores.
// ---------------------------------------------------------------------------
__global__ __launch_bounds__(256) void tr_fwd(const float* __restrict__ q,
                                              const float* __restrict__ k,
                                              const float* __restrict__ v,
                                              unsigned short* __restrict__ ttr)
{
    __shared__ float Ts[64][65];
    int tt     = blockIdx.x;          // t-tile 0..31
    int h      = blockIdx.y;          // 0..7
    int z      = blockIdx.z;          // tensor*4 + b
    int tensor = z >> 2;
    int b      = z & 3;
    int tid    = threadIdx.x;
    int t0     = tt * 64;

    const float* in = (tensor == 0) ? q : (tensor == 1) ? k : v;

    {
        int tl = tid >> 2, ec = (tid & 3) * 16;
        const float* src = in + ((size_t)b * 2048 + t0 + tl) * 512 + h * 64 + ec;
        #pragma unroll
        for (int m = 0; m < 4; m++) {
            float4 v4 = *(const float4*)(src + m * 4);
            Ts[tl][ec + m * 4 + 0] = v4.x;
            Ts[tl][ec + m * 4 + 1] = v4.y;
            Ts[tl][ec + m * 4 + 2] = v4.z;
            Ts[tl][ec + m * 4 + 3] = v4.w;
        }
    }
    __syncthreads();
    {
        int el = tid >> 2, tc = (tid & 3) * 16;
        size_t row = ((size_t)(tensor * 32 + b * 8 + h)) * 64 + el;
        unsigned short* dst = ttr + row * 2048 + t0 + tc;
        #pragma unroll
        for (int m = 0; m < 4; m++) {
            float a0 = Ts[tc + m * 4 + 0][el], a1 = Ts[tc + m * 4 + 1][el];
            float a2 = Ts[tc + m * 4 + 2][el], a3 = Ts[tc + m * 4 + 3][el];
            unsigned u0, u1;
            CVTPK(u0, a0, a1);
            CVTPK(u1, a2, a3);
            uint2 o; o.x = u0; o.y = u1;
            *(uint2*)(dst + m * 4) = o;
        }
    }
}

// ---------------------------------------------------------------------------
// Forward rFFT (ortho) via real-packing, reading contiguous bf16 series.
// Output bf16 planes P[bh*128+kk][1056]; Q plane carries extra 0.125 (1/sqrtE).
// V plane: within each 32-col tile, 8-elem chunks are stored at position
// chunk ^ ((row>>2)&3) (row = e or 64+e, block-uniform) so flash's linear-LDS
// V tile reads conflict-free.  Grid: g = e*96 + (tensor*32+bh).
// ---------------------------------------------------------------------------
__global__ __launch_bounds__(256) void fft_fwd(const unsigned short* __restrict__ ttr,
                                               unsigned short* __restrict__ Pq,
                                               unsigned short* __restrict__ Pk,
                                               unsigned short* __restrict__ Pv)
{
    __shared__ float2 buf[MM];
    __shared__ float2 tw[MM / 2];

    int g      = blockIdx.x;
    int p      = g % 96;              // tensor*32 + bh
    int e      = g / 96;              // 0..63
    int tensor = p / 32;
    int bh     = p % 32;
    int tid    = threadIdx.x;

    unsigned short* plane = (tensor == 0) ? Pq : (tensor == 1) ? Pk : Pv;
    float scl = (tensor == 0) ? (INV_SQRT_N * 0.125f) : INV_SQRT_N;
    int vk3 = (tensor == 2) ? (((e >> 2) & 3) << 3) : 0;   // V chunk swizzle

    for (int i = tid; i < MM / 2; i += 256) {
        float ang = -TWO_PI * (float)i / (float)MM;
        float sv, cv;
        __sincosf(ang, &sv, &cv);
        tw[i] = make_float2(cv, sv);
    }

    const unsigned short* src = ttr + ((size_t)p * 64 + e) * 2048;
    #pragma unroll
    for (int i = 0; i < 4; i++) {
        int j = tid + 256 * i;
        unsigned pr = *(const unsigned*)(src + 2 * j);   // x[2j], x[2j+1]
        float x0 = bf2f((unsigned short)(pr & 0xFFFFu));
        float x1 = bf2f((unsigned short)(pr >> 16));
        buf[__brev((unsigned)j) >> (32 - LOGM)] = make_float2(x0, x1);
    }
    __syncthreads();

    fft_stages_m(buf, tw, tid);

    unsigned short* dre = plane + ((size_t)bh * 128 + e) * NYP;
    unsigned short* dim_ = dre + (size_t)64 * NYP;

#define RPOINT(Ai, Bi, KKi, XR, XI) do {                                   \
        float Ex = 0.5f * (Ai.x + Bi.x), Ey = 0.5f * (Ai.y - Bi.y);        \
        float Dx = 0.5f * (Ai.x - Bi.x), Dy = 0.5f * (Ai.y + Bi.y);        \
        float Ox = Dy, Oy = -Dx;                                           \
        float th = -(TWO_PI / (float)NN) * (float)(KKi);                   \
        float sn, cs; __sincosf(th, &sn, &cs);                             \
        XR = (Ex + cs * Ox - sn * Oy) * scl;                               \
        XI = (Ey + cs * Oy + sn * Ox) * scl;                               \
    } while (0)

    #pragma unroll
    for (int i = 0; i < 2; i++) {
        int kk = 2 * tid + 512 * i;                  // even, 0..1022
        float2 A0 = buf[kk];
        float2 B0 = buf[(MM - kk) & (MM - 1)];
        float2 A1 = buf[kk + 1];
        float2 B1 = buf[MM - kk - 1];
        float Xr0, Xi0, Xr1, Xi1;
        RPOINT(A0, B0, kk, Xr0, Xi0);
        RPOINT(A1, B1, kk + 1, Xr1, Xi1);
        unsigned ur, ui;
        CVTPK(ur, Xr0, Xr1);
        CVTPK(ui, Xi0, Xi1);
        int ks = kk ^ vk3;                           // swizzle stays even
        *(unsigned*)(dre + ks)  = ur;
        *(unsigned*)(dim_ + ks) = ui;
    }
    // tail: kk = 1024 (real) + zero pads 1025..1055, as 16 u32 stores
    if (tid < 16) {
        unsigned ur = 0, ui = 0;
        if (tid == 0) {
            float2 A = buf[0];                        // A == Bc at kk=1024
            float sn, cs;
            __sincosf(-(TWO_PI / (float)NN) * 1024.0f, &sn, &cs);
            float Xr = (A.x + cs * A.y) * scl;        // Ex + cs*Ox
            float Xi = (sn * A.y) * scl;              // sn*Ox
            float zz = 0.f;
            CVTPK(ur, Xr, zz);
            CVTPK(ui, Xi, zz);
        }
        int ks = (1024 + 2 * tid) ^ vk3;
        *(unsigned*)(dre + ks)  = ur;
        *(unsigned*)(dim_ + ks) = ui;
    }
#undef RPOINT
}

// ---------------------------------------------------------------------------
// Transpose q,k planes [bh*128+kk][1056] -> [bh][1056][128].
// K rows are written with 16B chunks XOR-swizzled (chunk ^ (y&7)) so flash can
// DMA them linearly into LDS and still read bank-conflict-free (rule #21:
// inverse-swizzled source + swizzled read, linear LDS).
// ---------------------------------------------------------------------------
__global__ __launch_bounds__(256) void qkpack(const unsigned short* __restrict__ Pq,
                                              const unsigned short* __restrict__ Pk,
                                              unsigned short* __restrict__ Qp,
                                              unsigned short* __restrict__ Kp)
{
    __shared__ unsigned short Ts[32][136];
    int y0  = blockIdx.x * 32;
    int bh  = blockIdx.y;
    int tsr = blockIdx.z;
    int tid = threadIdx.x;

    const unsigned short* srcp = (tsr == 0) ? Pq : Pk;
    unsigned short* dstp       = (tsr == 0) ? Qp : Kp;

    {
        int kk = tid >> 1, seg = tid & 1;
        const unsigned short* sp = srcp + ((size_t)bh * 128 + kk) * NYP + y0 + seg * 16;
        uint4 va = *(const uint4*)sp;
        uint4 vb = *(const uint4*)(sp + 8);
        const unsigned short* pa = (const unsigned short*)&va;
        const unsigned short* pb = (const unsigned short*)&vb;
        #pragma unroll
        for (int j = 0; j < 8; j++) Ts[seg * 16 + j][kk] = pa[j];
        #pragma unroll
        for (int j = 0; j < 8; j++) Ts[seg * 16 + 8 + j][kk] = pb[j];
    }
    __syncthreads();
    {
        int y = tid >> 3, c = tid & 7;       // c: 32B pair (chunks 2c, 2c+1)
        uint4 lo = *(const uint4*)&Ts[y][c * 16];
        uint4 hi = *(const uint4*)&Ts[y][c * 16 + 8];
        char* rowb = (char*)(dstp + ((size_t)bh * NYP + y0 + y) * 128);
        if (tsr == 0) {
            *(uint4*)(rowb + c * 32)      = lo;
            *(uint4*)(rowb + c * 32 + 16) = hi;
        } else {
            int s = y & 7;
            *(uint4*)(rowb + (((2 * c)     ^ s) << 4)) = lo;
            *(uint4*)(rowb + (((2 * c + 1) ^ s) << 4)) = hi;
        }
    }
}

// ---------------------------------------------------------------------------
// MFMA flash attention, no-max softmax, y-split x2, XCD swizzle.
// K/V staged via global_load_lds into LDS double-buffer; counted vmcnt(4)
// keeps next-tile loads in flight across raw s_barriers (T3/T4); setprio (T5).
// numb layout: [half][bh][kk=0..127][x=0..1055] bf16, x contiguous.
// ---------------------------------------------------------------------------
struct FlashShared {
    union {
        struct {
            unsigned short Ks[2][32][128];   // 16 KB, chunk-XOR-swizzled rows
            unsigned short Vs[2][128][32];   // 16 KB, chunk-swizzled (fft_fwd)
        } kv;                                // 32 KB
        unsigned short OutT[128][72];        // 18 KB (epilogue only)
    } u;
    unsigned short Ps[4][16][40];            // 5 KB, wave-private
};

__global__ __launch_bounds__(256) void flash_mfma(
    const unsigned short* __restrict__ Qp,   // [bh][1056][128] bf16 (x0.125)
    const unsigned short* __restrict__ Kp,   // [bh][1056][128] bf16, swizzled
    const unsigned short* __restrict__ Vt,   // [bh*128+kk][1056] bf16, swizzled
    unsigned short* __restrict__ numb,       // [2][bh][128][1056] bf16
    float* __restrict__ lbuf)                // [2][bh*1056+x] fp32
{
    __shared__ FlashShared S;

    int g    = blockIdx.x;            // idx*32 + bh : g%8 == bh%8 (XCD pin)
    int bh   = g & 31;
    int idx  = g >> 5;                // 0..33
    int half = idx / 17;
    int x0   = (idx % 17) * 64;
    int tid  = threadIdx.x;
    int w    = tid >> 6;
    int lane = tid & 63;
    int qd   = lane >> 4;
    int col  = lane & 15;

    // ---- Q A-fragments: direct bf16 loads + sign trick ----
    int xrow = x0 + w * 16 + col;
    int xq   = min(xrow, 1024);
    const unsigned short* qb = Qp + ((size_t)bh * NYP + xq) * 128 + qd * 8;
    bhalf8 Are[4], Aim[4];
    #pragma unroll
    for (int ks = 0; ks < 4; ks++) Are[ks] = *(const bhalf8*)(qb + ks * 32);
    Aim[0] = Are[2];                       // k<64 : Qi
    Aim[1] = Are[3];
    #pragma unroll
    for (int ks = 0; ks < 2; ks++) {       // k>=64: -Qr
        bhalf8 t = Are[ks];
        unsigned* u = (unsigned*)&t;
        #pragma unroll
        for (int j = 0; j < 4; j++) u[j] ^= 0x80008000u;
        Aim[ks + 2] = t;
    }

    f32x4 O[8];
    #pragma unroll
    for (int n = 0; n < 8; n++) O[n] = (f32x4){0.f, 0.f, 0.f, 0.f};
    float Lacc[4] = {0.f, 0.f, 0.f, 0.f};

    int yt0 = half * 17, yt1 = min(33, yt0 + 17);

    // ---- per-wave DMA source pointers (bytes) ----
    const char* ksrc = (const char*)Kp
        + ((size_t)bh * NYP + (size_t)yt0 * 32 + w * 8) * 256 + lane * 16;
    const char* vbase = (const char*)Vt + (size_t)bh * 128 * (NYP * 2);
    const char* vsrc0 = vbase + ((size_t)(w * 32) + (lane >> 2)) * (NYP * 2)
                        + (size_t)yt0 * 64 + (lane & 3) * 16;
    const char* vsrc1 = vsrc0 + (size_t)16 * (NYP * 2);

    // swizzled K chunk offsets (ushort units), loop-invariant per lane
    int sw = col & 7;
    int kco[4];
    #pragma unroll
    for (int ks = 0; ks < 4; ks++) kco[ks] = ((ks * 4 + qd) ^ sw) * 8;
    // V chunk unswizzle: stored position of chunk qd in row (n*16+col)
    int vq = (qd ^ ((col >> 2) & 3)) * 8;

    // ---- prologue: stage tile yt0 ----
    {
        int pb = yt0 & 1;
        GLD16(ksrc,         &S.u.kv.Ks[pb][w * 8][0]);
        GLD16(ksrc + 1024,  &S.u.kv.Ks[pb][w * 8 + 4][0]);
        GLD16(vsrc0,        &S.u.kv.Vs[pb][w * 32][0]);
        GLD16(vsrc1,        &S.u.kv.Vs[pb][w * 32 + 16][0]);
        ksrc += 8192; vsrc0 += 64; vsrc1 += 64;
    }

    for (int yt = yt0; yt < yt1; yt++) {
        int cb = yt & 1, nb = cb ^ 1;
        if (yt + 1 < yt1) {
            // issue next tile's DMA (stays in flight across both barriers)
            GLD16(ksrc,         &S.u.kv.Ks[nb][w * 8][0]);
            GLD16(ksrc + 1024,  &S.u.kv.Ks[nb][w * 8 + 4][0]);
            GLD16(vsrc0,        &S.u.kv.Vs[nb][w * 32][0]);
            GLD16(vsrc1,        &S.u.kv.Vs[nb][w * 32 + 16][0]);
            ksrc += 8192; vsrc0 += 64; vsrc1 += 64;
            __builtin_amdgcn_sched_barrier(0);
            asm volatile("s_waitcnt vmcnt(4)" ::: "memory");   // cur tile done
        } else {
            __builtin_amdgcn_sched_barrier(0);
            asm volatile("s_waitcnt vmcnt(0)" ::: "memory");
        }
        __builtin_amdgcn_sched_barrier(0);
        __builtin_amdgcn_s_barrier();                          // all waves' DMA visible
        __builtin_amdgcn_sched_barrier(0);

        const unsigned short* k0 = &S.u.kv.Ks[cb][col][0];
        const unsigned short* k1 = &S.u.kv.Ks[cb][col + 16][0];

        // ---- QK ----
        f32x4 sre[2], sim[2];
        #pragma unroll
        for (int sc = 0; sc < 2; sc++) {
            sre[sc] = (f32x4){0.f, 0.f, 0.f, 0.f};
            sim[sc] = (f32x4){0.f, 0.f, 0.f, 0.f};
        }
        __builtin_amdgcn_s_setprio(1);
        #pragma unroll
        for (int ks = 0; ks < 4; ks++) {
            bhalf8 b0 = *(const bhalf8*)(k0 + kco[ks]);
            bhalf8 b1 = *(const bhalf8*)(k1 + kco[ks]);
            sre[0] = MFMA16(Are[ks], b0, sre[0]);
            sim[0] = MFMA16(Aim[ks], b0, sim[0]);
            sre[1] = MFMA16(Are[ks], b1, sre[1]);
            sim[1] = MFMA16(Aim[ks], b1, sim[1]);
        }
        __builtin_amdgcn_s_setprio(0);

        // ---- p = exp(sqrt(re^2+im^2))  (0.125/sqrtE folded into Q) ----
        #pragma unroll
        for (int r = 0; r < 4; r++) {
            float re0 = sre[0][r], im0 = sim[0][r];
            float re1 = sre[1][r], im1 = sim[1][r];
            float p0 = __expf(__builtin_amdgcn_sqrtf(fmaf(re0, re0, im0 * im0)));
            float p1 = __expf(__builtin_amdgcn_sqrtf(fmaf(re1, re1, im1 * im1)));
            Lacc[r] += p0 + p1;
            unsigned up;
            CVTPK(up, p0, p1);
            S.Ps[w][qd * 4 + r][col]      = (unsigned short)up;
            S.Ps[w][qd * 4 + r][col + 16] = (unsigned short)(up >> 16);
        }

        // ---- PV ----
        bhalf8 pa = *(const bhalf8*)&S.Ps[w][col][qd * 8];
        __builtin_amdgcn_s_setprio(1);
        #pragma unroll
        for (int n = 0; n < 8; n++) {
            bhalf8 bv = *(const bhalf8*)&S.u.kv.Vs[cb][n * 16 + col][vq];
            O[n] = MFMA16(pa, bv, O[n]);
        }
        __builtin_amdgcn_s_setprio(0);

        asm volatile("s_waitcnt lgkmcnt(0)" ::: "memory");     // reads retired
        __builtin_amdgcn_sched_barrier(0);
        __builtin_amdgcn_s_barrier();                          // safe to overwrite cb^1
        __builtin_amdgcn_sched_barrier(0);
    }

    // ---- l reduce + store ----
    size_t hofs = (size_t)half * 32 * NYP;
    #pragma unroll
    for (int r = 0; r < 4; r++) {
        float ls = Lacc[r];
        ls += __shfl_xor(ls, 1);
        ls += __shfl_xor(ls, 2);
        ls += __shfl_xor(ls, 4);
        ls += __shfl_xor(ls, 8);
        if (half == 1) ls -= 31.0f;        // zero-pad columns contributed 1 each
        int x = x0 + w * 16 + qd * 4 + r;
        if (x <= 1024 && col == 0) lbuf[hofs + (size_t)bh * NYP + x] = ls;
    }

    // ---- numerator: C-layout -> LDS overlay -> coalesced row writes ----
    __syncthreads();                       // Ks/Vs dead; safe to overlay
    #pragma unroll
    for (int n = 0; n < 8; n++) {
        unsigned u0, u1;
        CVTPK(u0, O[n][0], O[n][1]);
        CVTPK(u1, O[n][2], O[n][3]);
        *(unsigned*)&S.u.OutT[n * 16 + col][w * 16 + qd * 4]     = u0;
        *(unsigned*)&S.u.OutT[n * 16 + col][w * 16 + qd * 4 + 2] = u1;
    }
    __syncthreads();
    {
        int kk2 = tid >> 1, seg = tid & 1;
        int xg  = x0 + seg * 32;
        if (xg < NYP) {
            unsigned short* dst =
                numb + (((size_t)half * 32 + bh) * 128 + kk2) * NYP + xg;
            const unsigned short* srcl = &S.u.OutT[kk2][seg * 32];
            #pragma unroll
            for (int m = 0; m < 4; m++)
                *(uint4*)(dst + m * 8) = *(const uint4*)(srcl + m * 8);
        }
    }
}

// ---------------------------------------------------------------------------
// Inverse rFFT (ortho): combine halves (coalesced bf16 reads), packed irFFT,
// write contiguous staging st[bh*64+e][2048] fp32.
// ---------------------------------------------------------------------------
__global__ __launch_bounds__(256) void fft_inv(const unsigned short* __restrict__ numb,
                                               const float* __restrict__ lbuf,
                                               float* __restrict__ st)
{
    __shared__ float2 buf[MM];
    __shared__ float2 tw[MM / 2];

    int s   = blockIdx.x;          // bh*64 + e
    int e   = s & 63;
    int bh  = s >> 6;
    int tid = threadIdx.x;

    for (int i = tid; i < MM / 2; i += 256) {
        float ang = TWO_PI * (float)i / (float)MM;
        float sv, cv;
        __sincosf(ang, &sv, &cv);
        tw[i] = make_float2(cv, sv);
    }

    const size_t HS = (size_t)32 * 128 * NYP;
    const unsigned short* nbr = numb + ((size_t)bh * 128 + e) * NYP;
    const unsigned short* nbi = numb + ((size_t)bh * 128 + 64 + e) * NYP;
    const float* l0 = lbuf + (size_t)bh * NYP;
    const float* l1 = l0 + (size_t)32 * NYP;

    #pragma unroll
    for (int i = 0; i < 4; i++) {
        int kk = tid + 256 * i;
        int x1 = kk, x2 = 1024 - kk;
        float iv1 = 1.f / (l0[x1] + l1[x1]);
        float iv2 = 1.f / (l0[x2] + l1[x2]);
        float Ax = (bf2f(nbr[x1]) + bf2f(nbr[HS + x1])) * iv1;
        float Ay = (bf2f(nbi[x1]) + bf2f(nbi[HS + x1])) * iv1;
        float Bx = (bf2f(nbr[x2]) + bf2f(nbr[HS + x2])) * iv2;
        float By = -((bf2f(nbi[x2]) + bf2f(nbi[HS + x2])) * iv2);
        float Ex = 0.5f * (Ax + Bx), Ey = 0.5f * (Ay + By);
        float Dx = 0.5f * (Ax - Bx), Dy = 0.5f * (Ay - By);
        float th = (TWO_PI / (float)NN) * (float)kk;
        float sn, cs;
        __sincosf(th, &sn, &cs);
        float Ox = Dx * cs - Dy * sn;
        float Oy = Dx * sn + Dy * cs;
        buf[__brev((unsigned)kk) >> (32 - LOGM)] = make_float2(Ex - Oy, Ey + Ox);
    }
    __syncthreads();

    fft_stages_m(buf, tw, tid);

    float* dst = st + ((size_t)bh * 64 + e) * 2048;
    #pragma unroll
    for (int i = 0; i < 4; i++) {
        int j = tid + 256 * i;
        float2 z = buf[j];
        *(float2*)&dst[2 * j] = make_float2(z.x * INV_SCALE, z.y * INV_SCALE);
    }
}

// ---------------------------------------------------------------------------
// Final transpose: st[bh*64+e][t] -> out[b][t][h][e].  64x64 tiles via LDS.
// ---------------------------------------------------------------------------
__global__ __launch_bounds__(256) void out_tr(const float* __restrict__ st,
                                              float* __restrict__ out)
{
    __shared__ float Ts[64][65];
    int tt  = blockIdx.x;         // t-tile 0..31
    int h   = blockIdx.y;         // 0..7
    int b   = blockIdx.z;         // 0..3
    int tid = threadIdx.x;
    int bh  = b * 8 + h;

    {
        int e = tid >> 2, tc = (tid & 3) * 16;
        const float* src = st + ((size_t)bh * 64 + e) * 2048 + tt * 64 + tc;
        #pragma unroll
        for (int m = 0; m < 4; m++) {
            float4 v4 = *(const float4*)(src + m * 4);
            Ts[e][tc + m * 4 + 0] = v4.x;
            Ts[e][tc + m * 4 + 1] = v4.y;
            Ts[e][tc + m * 4 + 2] = v4.z;
            Ts[e][tc + m * 4 + 3] = v4.w;
        }
    }
    __syncthreads();
    {
        int t = tid >> 2, ec = (tid & 3) * 16;
        float* dst = out + (size_t)b * 2048 * 512 + (size_t)(tt * 64 + t) * 512
                     + h * 64 + ec;
        #pragma unroll
        for (int m = 0; m < 4; m++) {
            float4 v4;
            v4.x = Ts[ec + m * 4 + 0][t];
            v4.y = Ts[ec + m * 4 + 1][t];
            v4.z = Ts[ec + m * 4 + 2][t];
            v4.w = Ts[ec + m * 4 + 3][t];
            *(float4*)(dst + m * 4) = v4;
        }
    }
}

// ---------------------------------------------------------------------------
extern "C" void kernel_launch(void* const* d_in, const int* in_sizes, int n_in,
                              void* d_out, int out_size, void* d_ws, size_t ws_size,
                              hipStream_t stream)
{
    const float* q = (const float*)d_in[0];
    const float* k = (const float*)d_in[1];
    const float* v = (const float*)d_in[2];
    float* out = (float*)d_out;

    char* ws = (char*)d_ws;
    const size_t PL = (size_t)32 * 128 * NYP * sizeof(unsigned short); // 8.65 MB
    unsigned short* Pq = (unsigned short*)(ws);
    unsigned short* Pk = (unsigned short*)(ws + PL);
    unsigned short* Pv = (unsigned short*)(ws + 2 * PL);
    // ttr at 3PL (25.2 MB); dead after fft_fwd, then Qp/Kp reuse the space.
    unsigned short* ttr = (unsigned short*)(ws + 3 * PL);
    unsigned short* Qp = (unsigned short*)(ws + 3 * PL);
    unsigned short* Kp = (unsigned short*)(ws + 4 * PL);
    // numb aliases Pq+Pk (dead after qkpack): 2*PL exactly.
    unsigned short* numb = (unsigned short*)(ws);
    // st aliases Qp+Kp (dead after flash_mfma): 16.78 MB <= 2*PL.
    float* st   = (float*)(ws + 3 * PL);
    float* lbuf = (float*)(ws + 5 * PL);          // 270 KB; peak ws 51.2 MB

    hipLaunchKernelGGL(tr_fwd, dim3(32, 8, 12), dim3(256), 0, stream,
                       q, k, v, ttr);
    hipLaunchKernelGGL(fft_fwd, dim3(3 * 2048), dim3(256), 0, stream,
                       ttr, Pq, Pk, Pv);
    hipLaunchKernelGGL(qkpack, dim3(33, 32, 2), dim3(256), 0, stream,
                       Pq, Pk, Qp, Kp);
    hipLaunchKernelGGL(flash_mfma, dim3(1088), dim3(256), 0, stream,
                       Qp, Kp, Pv, numb, lbuf);
    hipLaunchKernelGGL(fft_inv, dim3(2048), dim3(256), 0, stream,
                       numb, lbuf, st);
    hipLaunchKernelGGL(out_tr, dim3(32, 8, 4), dim3(256), 0, stream,
                       st, out);
}

// Round 4
// 215.791 us; speedup vs baseline: 1.0801x; 1.0033x over previous
//
#include <hip/hip_runtime.h>
#include <hip/hip_bf16.h>
#include <math.h>

// B=4, L=S=2048, H=8, E=64, T=1.0.  I/O fp32.
// Pipeline: tr_fwd (coalesced transpose [B,T,H,E]->bf16 [tensor,bh,e][t])
// -> fft_fwd (real-packed 1024-pt FFT, bf16 planes; Q plane pre-scaled
//    0.125*log2e so flash softmax is exp2(sqrt(re^2+im^2)) directly;
//    V plane chunk-swizzled for conflict-free PV ds_reads)
// -> qkpack (K chunks XOR-swizzled at source for linear-LDS DMA) -> flash_mfma
// (global_load_lds K/V staging, LDS dbuf, counted vmcnt(4), raw s_barrier,
//  setprio around MFMA, cvt_pk packing) -> fft_inv -> out_tr.
// R12: flash was latency-bound (Occupancy 27%, grid 4.25 blk/CU). Split the
// y-range 4-ways (NH=4, grid 2176) for ~2x resident waves; numb grows to 4
// partial planes placed in free ws regions [0,2PL)+[5PL,7PL) with a runtime
// ws_size fallback to NH=2 (identical to R11 path). exp2 fold kills 8 v_mul.
#define LOGN  11
#define NN    2048
#define LOGM  10
#define MM    1024
#define NF    1025
#define NYP   1056         // NF padded to 33 tiles of 32 (pads zeroed)
#define TWO_PI 6.283185307179586f
#define INV_SQRT_N 0.022097086912079608f      // 1/sqrt(2048)
#define INV_SCALE  0.044194173824159216f      // 2/sqrt(2048)  (M*z -> out)
#define LOG2E      1.4426950408889634f

typedef __attribute__((ext_vector_type(8))) short bhalf8;
typedef __attribute__((ext_vector_type(4))) float f32x4;

#define MFMA16(a, b, c) __builtin_amdgcn_mfma_f32_16x16x32_bf16(a, b, c, 0, 0, 0)

#define GLD16(gp, lp)                                                              \
    __builtin_amdgcn_global_load_lds(                                              \
        (const __attribute__((address_space(1))) void*)(gp),                       \
        (__attribute__((address_space(3))) void*)(lp), 16, 0, 0)

#define CVTPK(dst, lo, hi) \
    asm("v_cvt_pk_bf16_f32 %0, %1, %2" : "=v"(dst) : "v"(lo), "v"(hi))

#define EXP2F(dst, src) \
    asm("v_exp_f32 %0, %1" : "=v"(dst) : "v"(src))

__device__ __forceinline__ unsigned short f2bf(float f) {
    union { float f; unsigned u; } v; v.f = f;
    unsigned r = v.u + 0x7FFFu + ((v.u >> 16) & 1u);   // RNE
    return (unsigned short)(r >> 16);
}
__device__ __forceinline__ float bf2f(unsigned short h) {
    union { unsigned u; float f; } v; v.u = ((unsigned)h) << 16;
    return v.f;
}

// ---------------------------------------------------------------------------
// 1024-pt complex DIT stages in LDS (input pre-bit-reversed).
// ---------------------------------------------------------------------------
__device__ __forceinline__ void fft_stages_m(float2* buf, const float2* tw, int tid)
{
    for (int st = 1; st <= LOGM; st++) {
        int half = 1 << (st - 1);
        #pragma unroll
        for (int it = 0; it < 2; it++) {
            int j   = tid + 256 * it;          // 512 butterflies
            int pos = j & (half - 1);
            int grp = j >> (st - 1);
            int i0  = (grp << st) + pos;
            int i1  = i0 + half;
            float2 w = tw[pos << (LOGM - st)];
            float2 a = buf[i0];
            float2 b = buf[i1];
            float2 bw = make_float2(b.x * w.x - b.y * w.y,
                                    b.x * w.y + b.y * w.x);
            buf[i0] = make_float2(a.x + bw.x, a.y + bw.y);
            buf[i1] = make_float2(a.x - bw.x, a.y - bw.y);
        }
        __syncthreads();
    }
}

// ---------------------------------------------------------------------------
// Input transpose: in[b][t][h][e] fp32 -> ttr[(tensor*32+bh)*64+e][t] bf16.
// 64x64 tiles via LDS; both global sides fully coalesced; packed u32x2 stores.
// ---------------------------------------------------------------------------
__global__ __launch_bounds__(256) void tr_fwd(const float* __restrict__ q,
                                              const float* __restrict__ k,
                                              const float* __restrict__ v,
                                              unsigned short* __restrict__ ttr)
{
    __shared__ float Ts[64][65];
    int tt     = blockIdx.x;          // t-tile 0..31
    int h      = blockIdx.y;          // 0..7
    int z      = blockIdx.z;          // tensor*4 + b
    int tensor = z >> 2;
    int b      = z & 3;
    int tid    = threadIdx.x;
    int t0     = tt * 64;

    const float* in = (tensor == 0) ? q : (tensor == 1) ? k : v;

    {
        int tl = tid >> 2, ec = (tid & 3) * 16;
        const float* src = in + ((size_t)b * 2048 + t0 + tl) * 512 + h * 64 + ec;
        #pragma unroll
        for (int m = 0; m < 4; m++) {
            float4 v4 = *(const float4*)(src + m * 4);
            Ts[tl][ec + m * 4 + 0] = v4.x;
            Ts[tl][ec + m * 4 + 1] = v4.y;
            Ts[tl][ec + m * 4 + 2] = v4.z;
            Ts[tl][ec + m * 4 + 3] = v4.w;
        }
    }
    __syncthreads();
    {
        int el = tid >> 2, tc = (tid & 3) * 16;
        size_t row = ((size_t)(tensor * 32 + b * 8 + h)) * 64 + el;
        unsigned short* dst = ttr + row * 2048 + t0 + tc;
        #pragma unroll
        for (int m = 0; m < 4; m++) {
            float a0 = Ts[tc + m * 4 + 0][el], a1 = Ts[tc + m * 4 + 1][el];
            float a2 = Ts[tc + m * 4 + 2][el], a3 = Ts[tc + m * 4 + 3][el];
            unsigned u0, u1;
            CVTPK(u0, a0, a1);
            CVTPK(u1, a2, a3);
            uint2 o; o.x = u0; o.y = u1;
            *(uint2*)(dst + m * 4) = o;
        }
    }
}

// ---------------------------------------------------------------------------
// Forward rFFT (ortho) via real-packing, reading contiguous bf16 series.
// Output bf16 planes P[bh*128+kk][1056]; Q plane carries 0.125*log2e (1/sqrtE
// + exp2 conversion).  V plane: 8-elem chunks stored at chunk ^ ((row>>2)&3)
// (row = e or 64+e, block-uniform) for conflict-free flash PV reads.
// Grid: g = e*96 + (tensor*32+bh).
// ---------------------------------------------------------------------------
__global__ __launch_bounds__(256) void fft_fwd(const unsigned short* __restrict__ ttr,
                                               unsigned short* __restrict__ Pq,
                                               unsigned short* __restrict__ Pk,
                                               unsigned short* __restrict__ Pv)
{
    __shared__ float2 buf[MM];
    __shared__ float2 tw[MM / 2];

    int g      = blockIdx.x;
    int p      = g % 96;              // tensor*32 + bh
    int e      = g / 96;              // 0..63
    int tensor = p / 32;
    int bh     = p % 32;
    int tid    = threadIdx.x;

    unsigned short* plane = (tensor == 0) ? Pq : (tensor == 1) ? Pk : Pv;
    float scl = (tensor == 0) ? (INV_SQRT_N * 0.125f * LOG2E) : INV_SQRT_N;
    int vk3 = (tensor == 2) ? (((e >> 2) & 3) << 3) : 0;   // V chunk swizzle

    for (int i = tid; i < MM / 2; i += 256) {
        float ang = -TWO_PI * (float)i / (float)MM;
        float sv, cv;
        __sincosf(ang, &sv, &cv);
        tw[i] = make_float2(cv, sv);
    }

    const unsigned short* src = ttr + ((size_t)p * 64 + e) * 2048;
    #pragma unroll
    for (int i = 0; i < 4; i++) {
        int j = tid + 256 * i;
        unsigned pr = *(const unsigned*)(src + 2 * j);   // x[2j], x[2j+1]
        float x0 = bf2f((unsigned short)(pr & 0xFFFFu));
        float x1 = bf2f((unsigned short)(pr >> 16));
        buf[__brev((unsigned)j) >> (32 - LOGM)] = make_float2(x0, x1);
    }
    __syncthreads();

    fft_stages_m(buf, tw, tid);

    unsigned short* dre = plane + ((size_t)bh * 128 + e) * NYP;
    unsigned short* dim_ = dre + (size_t)64 * NYP;

#define RPOINT(Ai, Bi, KKi, XR, XI) do {                                   \
        float Ex = 0.5f * (Ai.x + Bi.x), Ey = 0.5f * (Ai.y - Bi.y);        \
        float Dx = 0.5f * (Ai.x - Bi.x), Dy = 0.5f * (Ai.y + Bi.y);        \
        float Ox = Dy, Oy = -Dx;                                           \
        float th = -(TWO_PI / (float)NN) * (float)(KKi);                   \
        float sn, cs; __sincosf(th, &sn, &cs);                             \
        XR = (Ex + cs * Ox - sn * Oy) * scl;                               \
        XI = (Ey + cs * Oy + sn * Ox) * scl;                               \
    } while (0)

    #pragma unroll
    for (int i = 0; i < 2; i++) {
        int kk = 2 * tid + 512 * i;                  // even, 0..1022
        float2 A0 = buf[kk];
        float2 B0 = buf[(MM - kk) & (MM - 1)];
        float2 A1 = buf[kk + 1];
        float2 B1 = buf[MM - kk - 1];
        float Xr0, Xi0, Xr1, Xi1;
        RPOINT(A0, B0, kk, Xr0, Xi0);
        RPOINT(A1, B1, kk + 1, Xr1, Xi1);
        unsigned ur, ui;
        CVTPK(ur, Xr0, Xr1);
        CVTPK(ui, Xi0, Xi1);
        int ks = kk ^ vk3;                           // swizzle stays even
        *(unsigned*)(dre + ks)  = ur;
        *(unsigned*)(dim_ + ks) = ui;
    }
    // tail: kk = 1024 (real) + zero pads 1025..1055, as 16 u32 stores
    if (tid < 16) {
        unsigned ur = 0, ui = 0;
        if (tid == 0) {
            float2 A = buf[0];                        // A == Bc at kk=1024
            float sn, cs;
            __sincosf(-(TWO_PI / (float)NN) * 1024.0f, &sn, &cs);
            float Xr = (A.x + cs * A.y) * scl;        // Ex + cs*Ox
            float Xi = (sn * A.y) * scl;              // sn*Ox
            float zz = 0.f;
            CVTPK(ur, Xr, zz);
            CVTPK(ui, Xi, zz);
        }
        int ks = (1024 + 2 * tid) ^ vk3;
        *(unsigned*)(dre + ks)  = ur;
        *(unsigned*)(dim_ + ks) = ui;
    }
#undef RPOINT
}

// ---------------------------------------------------------------------------
// Transpose q,k planes [bh*128+kk][1056] -> [bh][1056][128].
// K rows are written with 16B chunks XOR-swizzled (chunk ^ (y&7)) so flash can
// DMA them linearly into LDS and still read bank-conflict-free (rule #21).
// ---------------------------------------------------------------------------
__global__ __launch_bounds__(256) void qkpack(const unsigned short* __restrict__ Pq,
                                              const unsigned short* __restrict__ Pk,
                                              unsigned short* __restrict__ Qp,
                                              unsigned short* __restrict__ Kp)
{
    __shared__ unsigned short Ts[32][136];
    int y0  = blockIdx.x * 32;
    int bh  = blockIdx.y;
    int tsr = blockIdx.z;
    int tid = threadIdx.x;

    const unsigned short* srcp = (tsr == 0) ? Pq : Pk;
    unsigned short* dstp       = (tsr == 0) ? Qp : Kp;

    {
        int kk = tid >> 1, seg = tid & 1;
        const unsigned short* sp = srcp + ((size_t)bh * 128 + kk) * NYP + y0 + seg * 16;
        uint4 va = *(const uint4*)sp;
        uint4 vb = *(const uint4*)(sp + 8);
        const unsigned short* pa = (const unsigned short*)&va;
        const unsigned short* pb = (const unsigned short*)&vb;
        #pragma unroll
        for (int j = 0; j < 8; j++) Ts[seg * 16 + j][kk] = pa[j];
        #pragma unroll
        for (int j = 0; j < 8; j++) Ts[seg * 16 + 8 + j][kk] = pb[j];
    }
    __syncthreads();
    {
        int y = tid >> 3, c = tid & 7;       // c: 32B pair (chunks 2c, 2c+1)
        uint4 lo = *(const uint4*)&Ts[y][c * 16];
        uint4 hi = *(const uint4*)&Ts[y][c * 16 + 8];
        char* rowb = (char*)(dstp + ((size_t)bh * NYP + y0 + y) * 128);
        if (tsr == 0) {
            *(uint4*)(rowb + c * 32)      = lo;
            *(uint4*)(rowb + c * 32 + 16) = hi;
        } else {
            int s = y & 7;
            *(uint4*)(rowb + (((2 * c)     ^ s) << 4)) = lo;
            *(uint4*)(rowb + (((2 * c + 1) ^ s) << 4)) = hi;
        }
    }
}

// ---------------------------------------------------------------------------
// MFMA flash attention, no-max softmax, y-split xNH, XCD swizzle.
// K/V staged via global_load_lds into LDS double-buffer; counted vmcnt(4)
// keeps next-tile loads in flight across raw s_barriers (T3/T4); setprio (T5).
// numb partial planes: [h][bh][kk=0..127][x=0..1055] bf16; planes 0,1 at nb0,
// planes 2,3 at nb1 (two disjoint ws regions).
// ---------------------------------------------------------------------------
struct FlashShared {
    union {
        struct {
            unsigned short Ks[2][32][128];   // 16 KB, chunk-XOR-swizzled rows
            unsigned short Vs[2][128][32];   // 16 KB, chunk-swizzled (fft_fwd)
        } kv;                                // 32 KB
        unsigned short OutT[128][72];        // 18 KB (epilogue only)
    } u;
    unsigned short Ps[4][16][40];            // 5 KB, wave-private
};

template<int NH>
__global__ __launch_bounds__(256) void flash_mfma(
    const unsigned short* __restrict__ Qp,   // [bh][1056][128] bf16 (scaled)
    const unsigned short* __restrict__ Kp,   // [bh][1056][128] bf16, swizzled
    const unsigned short* __restrict__ Vt,   // [bh*128+kk][1056] bf16, swizzled
    unsigned short* __restrict__ nb0,        // partial planes 0,1
    unsigned short* __restrict__ nb1,        // partial planes 2,3 (NH=4)
    float* __restrict__ lbuf)                // [NH][bh*1056+x] fp32
{
    __shared__ FlashShared S;

    int g    = blockIdx.x;            // idx*32 + bh : g%8 == bh%8 (XCD pin)
    int bh   = g & 31;
    int idx  = g >> 5;                // 0..17*NH-1
    int half = idx / 17;              // y-quarter (or y-half)
    int x0   = (idx % 17) * 64;
    int tid  = threadIdx.x;
    int w    = tid >> 6;
    int lane = tid & 63;
    int qd   = lane >> 4;
    int col  = lane & 15;

    // ---- Q A-fragments: direct bf16 loads + sign trick ----
    int xrow = x0 + w * 16 + col;
    int xq   = min(xrow, 1024);
    const unsigned short* qb = Qp + ((size_t)bh * NYP + xq) * 128 + qd * 8;
    bhalf8 Are[4], Aim[4];
    #pragma unroll
    for (int ks = 0; ks < 4; ks++) Are[ks] = *(const bhalf8*)(qb + ks * 32);
    Aim[0] = Are[2];                       // k<64 : Qi
    Aim[1] = Are[3];
    #pragma unroll
    for (int ks = 0; ks < 2; ks++) {       // k>=64: -Qr
        bhalf8 t = Are[ks];
        unsigned* u = (unsigned*)&t;
        #pragma unroll
        for (int j = 0; j < 4; j++) u[j] ^= 0x80008000u;
        Aim[ks + 2] = t;
    }

    f32x4 O[8];
    #pragma unroll
    for (int n = 0; n < 8; n++) O[n] = (f32x4){0.f, 0.f, 0.f, 0.f};
    float Lacc[4] = {0.f, 0.f, 0.f, 0.f};

    int yt0 = (half * 33) / NH, yt1 = ((half + 1) * 33) / NH;

    // ---- per-wave DMA source pointers (bytes) ----
    const char* ksrc = (const char*)Kp
        + ((size_t)bh * NYP + (size_t)yt0 * 32 + w * 8) * 256 + lane * 16;
    const char* vbase = (const char*)Vt + (size_t)bh * 128 * (NYP * 2);
    const char* vsrc0 = vbase + ((size_t)(w * 32) + (lane >> 2)) * (NYP * 2)
                        + (size_t)yt0 * 64 + (lane & 3) * 16;
    const char* vsrc1 = vsrc0 + (size_t)16 * (NYP * 2);

    // swizzled K chunk offsets (ushort units), loop-invariant per lane
    int sw = col & 7;
    int kco[4];
    #pragma unroll
    for (int ks = 0; ks < 4; ks++) kco[ks] = ((ks * 4 + qd) ^ sw) * 8;
    // V chunk unswizzle: stored position of chunk qd in row (n*16+col)
    int vq = (qd ^ ((col >> 2) & 3)) * 8;

    // ---- prologue: stage tile yt0 ----
    {
        int pb = yt0 & 1;
        GLD16(ksrc,         &S.u.kv.Ks[pb][w * 8][0]);
        GLD16(ksrc + 1024,  &S.u.kv.Ks[pb][w * 8 + 4][0]);
        GLD16(vsrc0,        &S.u.kv.Vs[pb][w * 32][0]);
        GLD16(vsrc1,        &S.u.kv.Vs[pb][w * 32 + 16][0]);
        ksrc += 8192; vsrc0 += 64; vsrc1 += 64;
    }

    for (int yt = yt0; yt < yt1; yt++) {
        int cb = yt & 1, nb = cb ^ 1;
        if (yt + 1 < yt1) {
            // issue next tile's DMA (stays in flight across both barriers)
            GLD16(ksrc,         &S.u.kv.Ks[nb][w * 8][0]);
            GLD16(ksrc + 1024,  &S.u.kv.Ks[nb][w * 8 + 4][0]);
            GLD16(vsrc0,        &S.u.kv.Vs[nb][w * 32][0]);
            GLD16(vsrc1,        &S.u.kv.Vs[nb][w * 32 + 16][0]);
            ksrc += 8192; vsrc0 += 64; vsrc1 += 64;
            __builtin_amdgcn_sched_barrier(0);
            asm volatile("s_waitcnt vmcnt(4)" ::: "memory");   // cur tile done
        } else {
            __builtin_amdgcn_sched_barrier(0);
            asm volatile("s_waitcnt vmcnt(0)" ::: "memory");
        }
        __builtin_amdgcn_sched_barrier(0);
        __builtin_amdgcn_s_barrier();                          // all waves' DMA visible
        __builtin_amdgcn_sched_barrier(0);

        const unsigned short* k0 = &S.u.kv.Ks[cb][col][0];
        const unsigned short* k1 = &S.u.kv.Ks[cb][col + 16][0];

        // ---- QK ----
        f32x4 sre[2], sim[2];
        #pragma unroll
        for (int sc = 0; sc < 2; sc++) {
            sre[sc] = (f32x4){0.f, 0.f, 0.f, 0.f};
            sim[sc] = (f32x4){0.f, 0.f, 0.f, 0.f};
        }
        __builtin_amdgcn_s_setprio(1);
        #pragma unroll
        for (int ks = 0; ks < 4; ks++) {
            bhalf8 b0 = *(const bhalf8*)(k0 + kco[ks]);
            bhalf8 b1 = *(const bhalf8*)(k1 + kco[ks]);
            sre[0] = MFMA16(Are[ks], b0, sre[0]);
            sim[0] = MFMA16(Aim[ks], b0, sim[0]);
            sre[1] = MFMA16(Are[ks], b1, sre[1]);
            sim[1] = MFMA16(Aim[ks], b1, sim[1]);
        }
        __builtin_amdgcn_s_setprio(0);

        // ---- p = exp2(sqrt(re^2+im^2))  (0.125*log2e folded into Q) ----
        #pragma unroll
        for (int r = 0; r < 4; r++) {
            float re0 = sre[0][r], im0 = sim[0][r];
            float re1 = sre[1][r], im1 = sim[1][r];
            float s0 = __builtin_amdgcn_sqrtf(fmaf(re0, re0, im0 * im0));
            float s1 = __builtin_amdgcn_sqrtf(fmaf(re1, re1, im1 * im1));
            float p0, p1;
            EXP2F(p0, s0);
            EXP2F(p1, s1);
            Lacc[r] += p0 + p1;
            unsigned up;
            CVTPK(up, p0, p1);
            S.Ps[w][qd * 4 + r][col]      = (unsigned short)up;
            S.Ps[w][qd * 4 + r][col + 16] = (unsigned short)(up >> 16);
        }

        // ---- PV ----
        bhalf8 pa = *(const bhalf8*)&S.Ps[w][col][qd * 8];
        __builtin_amdgcn_s_setprio(1);
        #pragma unroll
        for (int n = 0; n < 8; n++) {
            bhalf8 bv = *(const bhalf8*)&S.u.kv.Vs[cb][n * 16 + col][vq];
            O[n] = MFMA16(pa, bv, O[n]);
        }
        __builtin_amdgcn_s_setprio(0);

        asm volatile("s_waitcnt lgkmcnt(0)" ::: "memory");     // reads retired
        __builtin_amdgcn_sched_barrier(0);
        __builtin_amdgcn_s_barrier();                          // safe to overwrite cb^1
        __builtin_amdgcn_sched_barrier(0);
    }

    // ---- l reduce + store ----
    #pragma unroll
    for (int r = 0; r < 4; r++) {
        float ls = Lacc[r];
        ls += __shfl_xor(ls, 1);
        ls += __shfl_xor(ls, 2);
        ls += __shfl_xor(ls, 4);
        ls += __shfl_xor(ls, 8);
        if (yt1 == 33) ls -= 31.0f;        // zero-pad columns contributed 1 each
        int x = x0 + w * 16 + qd * 4 + r;
        if (x <= 1024 && col == 0)
            lbuf[((size_t)half * 32 + bh) * NYP + x] = ls;
    }

    // ---- numerator: C-layout -> LDS overlay -> coalesced row writes ----
    const size_t HSZ = (size_t)32 * 128 * NYP;
    unsigned short* nplane = (half < 2 ? nb0 : nb1) + (size_t)(half & 1) * HSZ;

    __syncthreads();                       // Ks/Vs dead; safe to overlay
    #pragma unroll
    for (int n = 0; n < 8; n++) {
        unsigned u0, u1;
        CVTPK(u0, O[n][0], O[n][1]);
        CVTPK(u1, O[n][2], O[n][3]);
        *(unsigned*)&S.u.OutT[n * 16 + col][w * 16 + qd * 4]     = u0;
        *(unsigned*)&S.u.OutT[n * 16 + col][w * 16 + qd * 4 + 2] = u1;
    }
    __syncthreads();
    {
        int kk2 = tid >> 1, seg = tid & 1;
        int xg  = x0 + seg * 32;
        if (xg < NYP) {
            unsigned short* dst = nplane + ((size_t)bh * 128 + kk2) * NYP + xg;
            const unsigned short* srcl = &S.u.OutT[kk2][seg * 32];
            #pragma unroll
            for (int m = 0; m < 4; m++)
                *(uint4*)(dst + m * 8) = *(const uint4*)(srcl + m * 8);
        }
    }
}

// ---------------------------------------------------------------------------
// Inverse rFFT (ortho): combine NH partial planes (coalesced bf16 reads),
// packed irFFT, write contiguous staging st[bh*64+e][2048] fp32.
// ---------------------------------------------------------------------------
template<int NH>
__global__ __launch_bounds__(256) void fft_inv(const unsigned short* __restrict__ nb0,
                                               const unsigned short* __restrict__ nb1,
                                               const float* __restrict__ lbuf,
                                               float* __restrict__ st)
{
    __shared__ float2 buf[MM];
    __shared__ float2 tw[MM / 2];

    int s   = blockIdx.x;          // bh*64 + e
    int e   = s & 63;
    int bh  = s >> 6;
    int tid = threadIdx.x;

    for (int i = tid; i < MM / 2; i += 256) {
        float ang = TWO_PI * (float)i / (float)MM;
        float sv, cv;
        __sincosf(ang, &sv, &cv);
        tw[i] = make_float2(cv, sv);
    }

    const size_t HSZ = (size_t)32 * 128 * NYP;
    const unsigned short* pre[NH];
    const unsigned short* pim[NH];
    const float* lb[NH];
    #pragma unroll
    for (int h = 0; h < NH; h++) {
        const unsigned short* base = (h < 2 ? nb0 : nb1) + (size_t)(h & 1) * HSZ;
        pre[h] = base + ((size_t)bh * 128 + e) * NYP;
        pim[h] = base + ((size_t)bh * 128 + 64 + e) * NYP;
        lb[h]  = lbuf + ((size_t)h * 32 + bh) * NYP;
    }

    #pragma unroll
    for (int i = 0; i < 4; i++) {
        int kk = tid + 256 * i;
        int x1 = kk, x2 = 1024 - kk;
        float d1 = 0.f, d2 = 0.f;
        float Axs = 0.f, Ays = 0.f, Bxs = 0.f, Bys = 0.f;
        #pragma unroll
        for (int h = 0; h < NH; h++) {
            d1 += lb[h][x1];
            d2 += lb[h][x2];
            Axs += bf2f(pre[h][x1]);
            Ays += bf2f(pim[h][x1]);
            Bxs += bf2f(pre[h][x2]);
            Bys += bf2f(pim[h][x2]);
        }
        float iv1 = 1.f / d1, iv2 = 1.f / d2;
        float Ax = Axs * iv1, Ay = Ays * iv1;
        float Bx = Bxs * iv2, By = -(Bys * iv2);
        float Ex = 0.5f * (Ax + Bx), Ey = 0.5f * (Ay + By);
        float Dx = 0.5f * (Ax - Bx), Dy = 0.5f * (Ay - By);
        float th = (TWO_PI / (float)NN) * (float)kk;
        float sn, cs;
        __sincosf(th, &sn, &cs);
        float Ox = Dx * cs - Dy * sn;
        float Oy = Dx * sn + Dy * cs;
        buf[__brev((unsigned)kk) >> (32 - LOGM)] = make_float2(Ex - Oy, Ey + Ox);
    }
    __syncthreads();

    fft_stages_m(buf, tw, tid);

    float* dst = st + ((size_t)bh * 64 + e) * 2048;
    #pragma unroll
    for (int i = 0; i < 4; i++) {
        int j = tid + 256 * i;
        float2 z = buf[j];
        *(float2*)&dst[2 * j] = make_float2(z.x * INV_SCALE, z.y * INV_SCALE);
    }
}

// ---------------------------------------------------------------------------
// Final transpose: st[bh*64+e][t] -> out[b][t][h][e].  64x64 tiles via LDS.
// ---------------------------------------------------------------------------
__global__ __launch_bounds__(256) void out_tr(const float* __restrict__ st,
                                              float* __restrict__ out)
{
    __shared__ float Ts[64][65];
    int tt  = blockIdx.x;         // t-tile 0..31
    int h   = blockIdx.y;         // 0..7
    int b   = blockIdx.z;         // 0..3
    int tid = threadIdx.x;
    int bh  = b * 8 + h;

    {
        int e = tid >> 2, tc = (tid & 3) * 16;
        const float* src = st + ((size_t)bh * 64 + e) * 2048 + tt * 64 + tc;
        #pragma unroll
        for (int m = 0; m < 4; m++) {
            float4 v4 = *(const float4*)(src + m * 4);
            Ts[e][tc + m * 4 + 0] = v4.x;
            Ts[e][tc + m * 4 + 1] = v4.y;
            Ts[e][tc + m * 4 + 2] = v4.z;
            Ts[e][tc + m * 4 + 3] = v4.w;
        }
    }
    __syncthreads();
    {
        int t = tid >> 2, ec = (tid & 3) * 16;
        float* dst = out + (size_t)b * 2048 * 512 + (size_t)(tt * 64 + t) * 512
                     + h * 64 + ec;
        #pragma unroll
        for (int m = 0; m < 4; m++) {
            float4 v4;
            v4.x = Ts[ec + m * 4 + 0][t];
            v4.y = Ts[ec + m * 4 + 1][t];
            v4.z = Ts[ec + m * 4 + 2][t];
            v4.w = Ts[ec + m * 4 + 3][t];
            *(float4*)(dst + m * 4) = v4;
        }
    }
}

// ---------------------------------------------------------------------------
extern "C" void kernel_launch(void* const* d_in, const int* in_sizes, int n_in,
                              void* d_out, int out_size, void* d_ws, size_t ws_size,
                              hipStream_t stream)
{
    const float* q = (const float*)d_in[0];
    const float* k = (const float*)d_in[1];
    const float* v = (const float*)d_in[2];
    float* out = (float*)d_out;

    char* ws = (char*)d_ws;
    const size_t PL = (size_t)32 * 128 * NYP * sizeof(unsigned short); // 8.65 MB
    unsigned short* Pq = (unsigned short*)(ws);
    unsigned short* Pk = (unsigned short*)(ws + PL);
    unsigned short* Pv = (unsigned short*)(ws + 2 * PL);
    // ttr at 3PL (25.2 MB); dead after fft_fwd, then Qp/Kp reuse the space.
    unsigned short* ttr = (unsigned short*)(ws + 3 * PL);
    unsigned short* Qp = (unsigned short*)(ws + 3 * PL);
    unsigned short* Kp = (unsigned short*)(ws + 4 * PL);
    // st aliases Qp+Kp (dead after flash_mfma): 16.78 MB; ends before 5PL.
    float* st = (float*)(ws + 3 * PL);

    // NH=4 needs: planes 0,1 at [0,2PL) (Pq,Pk dead) + planes 2,3 at
    // [5PL,7PL) + lbuf at 7PL.  Fall back to NH=2 if ws is too small.
    const size_t lbuf4 = (size_t)4 * 32 * NYP * sizeof(float);
    bool big = ws_size >= 7 * PL + lbuf4;

    hipLaunchKernelGGL(tr_fwd, dim3(32, 8, 12), dim3(256), 0, stream,
                       q, k, v, ttr);
    hipLaunchKernelGGL(fft_fwd, dim3(3 * 2048), dim3(256), 0, stream,
                       ttr, Pq, Pk, Pv);
    hipLaunchKernelGGL(qkpack, dim3(33, 32, 2), dim3(256), 0, stream,
                       Pq, Pk, Qp, Kp);

    if (big) {
        unsigned short* nb0 = (unsigned short*)(ws);
        unsigned short* nb1 = (unsigned short*)(ws + 5 * PL);
        float* lbuf = (float*)(ws + 7 * PL);
        hipLaunchKernelGGL((flash_mfma<4>), dim3(17 * 4 * 32), dim3(256), 0, stream,
                           Qp, Kp, Pv, nb0, nb1, lbuf);
        hipLaunchKernelGGL((fft_inv<4>), dim3(2048), dim3(256), 0, stream,
                           nb0, nb1, lbuf, st);
    } else {
        unsigned short* nb0 = (unsigned short*)(ws);
        float* lbuf = (float*)(ws + 5 * PL);
        hipLaunchKernelGGL((flash_mfma<2>), dim3(17 * 2 * 32), dim3(256), 0, stream,
                           Qp, Kp, Pv, nb0, nb0, lbuf);
        hipLaunchKernelGGL((fft_inv<2>), dim3(2048), dim3(256), 0, stream,
                           nb0, nb0, lbuf, st);
    }

    hipLaunchKernelGGL(out_tr, dim3(32, 8, 4), dim3(256), 0, stream,
                       st, out);
}

// Round 5
// 207.257 us; speedup vs baseline: 1.1246x; 1.0412x over previous
//
#include <hip/hip_runtime.h>
#include <hip/hip_bf16.h>
#include <math.h>

// B=4, L=S=2048, H=8, E=64, T=1.0.  I/O fp32.
// Pipeline: tr_fwd (coalesced transpose [B,T,H,E]->bf16 [tensor,bh,e][t])
// -> fft_fwd (real-packed 1024-pt radix-4 FFT, bf16 planes; Q plane pre-scaled
//    0.125*log2e so flash softmax is exp2(sqrt(re^2+im^2)) directly;
//    V plane chunk-swizzled for conflict-free PV ds_reads)
// -> qkpack (K chunks XOR-swizzled at source for linear-LDS DMA) -> flash_mfma
// (global_load_lds K/V staging, LDS dbuf, counted vmcnt(4), raw s_barrier,
//  setprio around MFMA, cvt_pk packing, NH=4 y-split) -> fft_inv -> out_tr.
// R13: FFT stage loops radix-2 -> radix-4 (5 stages, half the LDS round-trips
// and barriers, 25% fewer cmuls; base-4 digit-reversed input; 768-entry tw).
#define LOGN  11
#define NN    2048
#define LOGM  10
#define MM    1024
#define NF    1025
#define NYP   1056         // NF padded to 33 tiles of 32 (pads zeroed)
#define TWO_PI 6.283185307179586f
#define INV_SQRT_N 0.022097086912079608f      // 1/sqrt(2048)
#define INV_SCALE  0.044194173824159216f      // 2/sqrt(2048)  (M*z -> out)
#define LOG2E      1.4426950408889634f

typedef __attribute__((ext_vector_type(8))) short bhalf8;
typedef __attribute__((ext_vector_type(4))) float f32x4;

#define MFMA16(a, b, c) __builtin_amdgcn_mfma_f32_16x16x32_bf16(a, b, c, 0, 0, 0)

#define GLD16(gp, lp)                                                              \
    __builtin_amdgcn_global_load_lds(                                              \
        (const __attribute__((address_space(1))) void*)(gp),                       \
        (__attribute__((address_space(3))) void*)(lp), 16, 0, 0)

#define CVTPK(dst, lo, hi) \
    asm("v_cvt_pk_bf16_f32 %0, %1, %2" : "=v"(dst) : "v"(lo), "v"(hi))

#define EXP2F(dst, src) \
    asm("v_exp_f32 %0, %1" : "=v"(dst) : "v"(src))

__device__ __forceinline__ unsigned short f2bf(float f) {
    union { float f; unsigned u; } v; v.f = f;
    unsigned r = v.u + 0x7FFFu + ((v.u >> 16) & 1u);   // RNE
    return (unsigned short)(r >> 16);
}
__device__ __forceinline__ float bf2f(unsigned short h) {
    union { unsigned u; float f; } v; v.u = ((unsigned)h) << 16;
    return v.f;
}

// base-4 digit reversal of a 10-bit index: pair-swapped bit reversal
__device__ __forceinline__ int dr4_10(unsigned j) {
    unsigned r = __brev(j) >> 22;
    return (int)(((r & 0x155u) << 1) | ((r >> 1) & 0x155u));
}

// ---------------------------------------------------------------------------
// 1024-pt complex radix-4 DIT stages in LDS (input base-4 digit-reversed).
// tw: 768 entries, tw[i] = (cos, sin) of (FWD ? -1 : +1)*2*pi*i/1024.
// Butterfly: a,b,c,d (twiddled) ->
//   y0 = (a+c)+(b+d);  y2 = (a+c)-(b+d)
//   y1 = (a-c) -+ j(b-d);  y3 = (a-c) +- j(b-d)   (fwd: -j on y1)
// ---------------------------------------------------------------------------
template<bool FWD>
__device__ __forceinline__ void fft_r4_1024(float2* buf, const float2* tw, int tid)
{
    // stage 0 (L=1): twiddles are all 1; 32B-contiguous per thread
    {
        int i0 = tid * 4;
        float2 a = buf[i0], b = buf[i0 + 1], c = buf[i0 + 2], d = buf[i0 + 3];
        float2 apc = make_float2(a.x + c.x, a.y + c.y);
        float2 amc = make_float2(a.x - c.x, a.y - c.y);
        float2 bpd = make_float2(b.x + d.x, b.y + d.y);
        float2 bmd = make_float2(b.x - d.x, b.y - d.y);
        buf[i0]     = make_float2(apc.x + bpd.x, apc.y + bpd.y);
        buf[i0 + 2] = make_float2(apc.x - bpd.x, apc.y - bpd.y);
        if (FWD) {
            buf[i0 + 1] = make_float2(amc.x + bmd.y, amc.y - bmd.x);
            buf[i0 + 3] = make_float2(amc.x - bmd.y, amc.y + bmd.x);
        } else {
            buf[i0 + 1] = make_float2(amc.x - bmd.y, amc.y + bmd.x);
            buf[i0 + 3] = make_float2(amc.x + bmd.y, amc.y - bmd.x);
        }
        __syncthreads();
    }
    #pragma unroll
    for (int s = 1; s < 5; s++) {
        int L  = 1 << (2 * s);
        int p  = tid & (L - 1);
        int i0 = ((tid >> (2 * s)) << (2 * s + 2)) + p;
        int e  = p << (8 - 2 * s);
        float2 w1 = tw[e], w2 = tw[2 * e], w3 = tw[3 * e];
        float2 a  = buf[i0];
        float2 xb = buf[i0 + L], xc = buf[i0 + 2 * L], xd = buf[i0 + 3 * L];
        float2 b = make_float2(xb.x * w1.x - xb.y * w1.y, xb.x * w1.y + xb.y * w1.x);
        float2 c = make_float2(xc.x * w2.x - xc.y * w2.y, xc.x * w2.y + xc.y * w2.x);
        float2 d = make_float2(xd.x * w3.x - xd.y * w3.y, xd.x * w3.y + xd.y * w3.x);
        float2 apc = make_float2(a.x + c.x, a.y + c.y);
        float2 amc = make_float2(a.x - c.x, a.y - c.y);
        float2 bpd = make_float2(b.x + d.x, b.y + d.y);
        float2 bmd = make_float2(b.x - d.x, b.y - d.y);
        buf[i0]         = make_float2(apc.x + bpd.x, apc.y + bpd.y);
        buf[i0 + 2 * L] = make_float2(apc.x - bpd.x, apc.y - bpd.y);
        if (FWD) {
            buf[i0 + L]     = make_float2(amc.x + bmd.y, amc.y - bmd.x);
            buf[i0 + 3 * L] = make_float2(amc.x - bmd.y, amc.y + bmd.x);
        } else {
            buf[i0 + L]     = make_float2(amc.x - bmd.y, amc.y + bmd.x);
            buf[i0 + 3 * L] = make_float2(amc.x + bmd.y, amc.y - bmd.x);
        }
        __syncthreads();
    }
}

// ---------------------------------------------------------------------------
// Input transpose: in[b][t][h][e] fp32 -> ttr[(tensor*32+bh)*64+e][t] bf16.
// 64x64 tiles via LDS; both global sides fully coalesced; packed u32x2 stores.
// ---------------------------------------------------------------------------
__global__ __launch_bounds__(256) void tr_fwd(const float* __restrict__ q,
                                              const float* __restrict__ k,
                                              const float* __restrict__ v,
                                              unsigned short* __restrict__ ttr)
{
    __shared__ float Ts[64][65];
    int tt     = blockIdx.x;          // t-tile 0..31
    int h      = blockIdx.y;          // 0..7
    int z      = blockIdx.z;          // tensor*4 + b
    int tensor = z >> 2;
    int b      = z & 3;
    int tid    = threadIdx.x;
    int t0     = tt * 64;

    const float* in = (tensor == 0) ? q : (tensor == 1) ? k : v;

    {
        int tl = tid >> 2, ec = (tid & 3) * 16;
        const float* src = in + ((size_t)b * 2048 + t0 + tl) * 512 + h * 64 + ec;
        #pragma unroll
        for (int m = 0; m < 4; m++) {
            float4 v4 = *(const float4*)(src + m * 4);
            Ts[tl][ec + m * 4 + 0] = v4.x;
            Ts[tl][ec + m * 4 + 1] = v4.y;
            Ts[tl][ec + m * 4 + 2] = v4.z;
            Ts[tl][ec + m * 4 + 3] = v4.w;
        }
    }
    __syncthreads();
    {
        int el = tid >> 2, tc = (tid & 3) * 16;
        size_t row = ((size_t)(tensor * 32 + b * 8 + h)) * 64 + el;
        unsigned short* dst = ttr + row * 2048 + t0 + tc;
        #pragma unroll
        for (int m = 0; m < 4; m++) {
            float a0 = Ts[tc + m * 4 + 0][el], a1 = Ts[tc + m * 4 + 1][el];
            float a2 = Ts[tc + m * 4 + 2][el], a3 = Ts[tc + m * 4 + 3][el];
            unsigned u0, u1;
            CVTPK(u0, a0, a1);
            CVTPK(u1, a2, a3);
            uint2 o; o.x = u0; o.y = u1;
            *(uint2*)(dst + m * 4) = o;
        }
    }
}

// ---------------------------------------------------------------------------
// Forward rFFT (ortho) via real-packing, reading contiguous bf16 series.
// Output bf16 planes P[bh*128+kk][1056]; Q plane carries 0.125*log2e (1/sqrtE
// + exp2 conversion).  V plane: 8-elem chunks stored at chunk ^ ((row>>2)&3)
// (row = e or 64+e, block-uniform) for conflict-free flash PV reads.
// Grid: g = e*96 + (tensor*32+bh).
// ---------------------------------------------------------------------------
__global__ __launch_bounds__(256) void fft_fwd(const unsigned short* __restrict__ ttr,
                                               unsigned short* __restrict__ Pq,
                                               unsigned short* __restrict__ Pk,
                                               unsigned short* __restrict__ Pv)
{
    __shared__ float2 buf[MM];
    __shared__ float2 tw[768];

    int g      = blockIdx.x;
    int p      = g % 96;              // tensor*32 + bh
    int e      = g / 96;              // 0..63
    int tensor = p / 32;
    int bh     = p % 32;
    int tid    = threadIdx.x;

    unsigned short* plane = (tensor == 0) ? Pq : (tensor == 1) ? Pk : Pv;
    float scl = (tensor == 0) ? (INV_SQRT_N * 0.125f * LOG2E) : INV_SQRT_N;
    int vk3 = (tensor == 2) ? (((e >> 2) & 3) << 3) : 0;   // V chunk swizzle

    #pragma unroll
    for (int i = tid; i < 768; i += 256) {
        float ang = -TWO_PI * (float)i / (float)MM;
        float sv, cv;
        __sincosf(ang, &sv, &cv);
        tw[i] = make_float2(cv, sv);
    }

    const unsigned short* src = ttr + ((size_t)p * 64 + e) * 2048;
    #pragma unroll
    for (int i = 0; i < 4; i++) {
        int j = tid + 256 * i;
        unsigned pr = *(const unsigned*)(src + 2 * j);   // x[2j], x[2j+1]
        float x0 = bf2f((unsigned short)(pr & 0xFFFFu));
        float x1 = bf2f((unsigned short)(pr >> 16));
        buf[dr4_10((unsigned)j)] = make_float2(x0, x1);
    }
    __syncthreads();

    fft_r4_1024<true>(buf, tw, tid);

    unsigned short* dre = plane + ((size_t)bh * 128 + e) * NYP;
    unsigned short* dim_ = dre + (size_t)64 * NYP;

#define RPOINT(Ai, Bi, KKi, XR, XI) do {                                   \
        float Ex = 0.5f * (Ai.x + Bi.x), Ey = 0.5f * (Ai.y - Bi.y);        \
        float Dx = 0.5f * (Ai.x - Bi.x), Dy = 0.5f * (Ai.y + Bi.y);        \
        float Ox = Dy, Oy = -Dx;                                           \
        float th = -(TWO_PI / (float)NN) * (float)(KKi);                   \
        float sn, cs; __sincosf(th, &sn, &cs);                             \
        XR = (Ex + cs * Ox - sn * Oy) * scl;                               \
        XI = (Ey + cs * Oy + sn * Ox) * scl;                               \
    } while (0)

    #pragma unroll
    for (int i = 0; i < 2; i++) {
        int kk = 2 * tid + 512 * i;                  // even, 0..1022
        float2 A0 = buf[kk];
        float2 B0 = buf[(MM - kk) & (MM - 1)];
        float2 A1 = buf[kk + 1];
        float2 B1 = buf[MM - kk - 1];
        float Xr0, Xi0, Xr1, Xi1;
        RPOINT(A0, B0, kk, Xr0, Xi0);
        RPOINT(A1, B1, kk + 1, Xr1, Xi1);
        unsigned ur, ui;
        CVTPK(ur, Xr0, Xr1);
        CVTPK(ui, Xi0, Xi1);
        int ks = kk ^ vk3;                           // swizzle stays even
        *(unsigned*)(dre + ks)  = ur;
        *(unsigned*)(dim_ + ks) = ui;
    }
    // tail: kk = 1024 (real) + zero pads 1025..1055, as 16 u32 stores
    if (tid < 16) {
        unsigned ur = 0, ui = 0;
        if (tid == 0) {
            float2 A = buf[0];                        // A == Bc at kk=1024
            float sn, cs;
            __sincosf(-(TWO_PI / (float)NN) * 1024.0f, &sn, &cs);
            float Xr = (A.x + cs * A.y) * scl;        // Ex + cs*Ox
            float Xi = (sn * A.y) * scl;              // sn*Ox
            float zz = 0.f;
            CVTPK(ur, Xr, zz);
            CVTPK(ui, Xi, zz);
        }
        int ks = (1024 + 2 * tid) ^ vk3;
        *(unsigned*)(dre + ks)  = ur;
        *(unsigned*)(dim_ + ks) = ui;
    }
#undef RPOINT
}

// ---------------------------------------------------------------------------
// Transpose q,k planes [bh*128+kk][1056] -> [bh][1056][128].
// K rows are written with 16B chunks XOR-swizzled (chunk ^ (y&7)) so flash can
// DMA them linearly into LDS and still read bank-conflict-free (rule #21).
// ---------------------------------------------------------------------------
__global__ __launch_bounds__(256) void qkpack(const unsigned short* __restrict__ Pq,
                                              const unsigned short* __restrict__ Pk,
                                              unsigned short* __restrict__ Qp,
                                              unsigned short* __restrict__ Kp)
{
    __shared__ unsigned short Ts[32][136];
    int y0  = blockIdx.x * 32;
    int bh  = blockIdx.y;
    int tsr = blockIdx.z;
    int tid = threadIdx.x;

    const unsigned short* srcp = (tsr == 0) ? Pq : Pk;
    unsigned short* dstp       = (tsr == 0) ? Qp : Kp;

    {
        int kk = tid >> 1, seg = tid & 1;
        const unsigned short* sp = srcp + ((size_t)bh * 128 + kk) * NYP + y0 + seg * 16;
        uint4 va = *(const uint4*)sp;
        uint4 vb = *(const uint4*)(sp + 8);
        const unsigned short* pa = (const unsigned short*)&va;
        const unsigned short* pb = (const unsigned short*)&vb;
        #pragma unroll
        for (int j = 0; j < 8; j++) Ts[seg * 16 + j][kk] = pa[j];
        #pragma unroll
        for (int j = 0; j < 8; j++) Ts[seg * 16 + 8 + j][kk] = pb[j];
    }
    __syncthreads();
    {
        int y = tid >> 3, c = tid & 7;       // c: 32B pair (chunks 2c, 2c+1)
        uint4 lo = *(const uint4*)&Ts[y][c * 16];
        uint4 hi = *(const uint4*)&Ts[y][c * 16 + 8];
        char* rowb = (char*)(dstp + ((size_t)bh * NYP + y0 + y) * 128);
        if (tsr == 0) {
            *(uint4*)(rowb + c * 32)      = lo;
            *(uint4*)(rowb + c * 32 + 16) = hi;
        } else {
            int s = y & 7;
            *(uint4*)(rowb + (((2 * c)     ^ s) << 4)) = lo;
            *(uint4*)(rowb + (((2 * c + 1) ^ s) << 4)) = hi;
        }
    }
}

// ---------------------------------------------------------------------------
// MFMA flash attention, no-max softmax, y-split xNH, XCD swizzle.
// K/V staged via global_load_lds into LDS double-buffer; counted vmcnt(4)
// keeps next-tile loads in flight across raw s_barriers (T3/T4); setprio (T5).
// numb partial planes: [h][bh][kk=0..127][x=0..1055] bf16; planes 0,1 at nb0,
// planes 2,3 at nb1 (two disjoint ws regions).
// ---------------------------------------------------------------------------
struct FlashShared {
    union {
        struct {
            unsigned short Ks[2][32][128];   // 16 KB, chunk-XOR-swizzled rows
            unsigned short Vs[2][128][32];   // 16 KB, chunk-swizzled (fft_fwd)
        } kv;                                // 32 KB
        unsigned short OutT[128][72];        // 18 KB (epilogue only)
    } u;
    unsigned short Ps[4][16][40];            // 5 KB, wave-private
};

template<int NH>
__global__ __launch_bounds__(256) void flash_mfma(
    const unsigned short* __restrict__ Qp,   // [bh][1056][128] bf16 (scaled)
    const unsigned short* __restrict__ Kp,   // [bh][1056][128] bf16, swizzled
    const unsigned short* __restrict__ Vt,   // [bh*128+kk][1056] bf16, swizzled
    unsigned short* __restrict__ nb0,        // partial planes 0,1
    unsigned short* __restrict__ nb1,        // partial planes 2,3 (NH=4)
    float* __restrict__ lbuf)                // [NH][bh*1056+x] fp32
{
    __shared__ FlashShared S;

    int g    = blockIdx.x;            // idx*32 + bh : g%8 == bh%8 (XCD pin)
    int bh   = g & 31;
    int idx  = g >> 5;                // 0..17*NH-1
    int half = idx / 17;              // y-quarter (or y-half)
    int x0   = (idx % 17) * 64;
    int tid  = threadIdx.x;
    int w    = tid >> 6;
    int lane = tid & 63;
    int qd   = lane >> 4;
    int col  = lane & 15;

    // ---- Q A-fragments: direct bf16 loads + sign trick ----
    int xrow = x0 + w * 16 + col;
    int xq   = min(xrow, 1024);
    const unsigned short* qb = Qp + ((size_t)bh * NYP + xq) * 128 + qd * 8;
    bhalf8 Are[4], Aim[4];
    #pragma unroll
    for (int ks = 0; ks < 4; ks++) Are[ks] = *(const bhalf8*)(qb + ks * 32);
    Aim[0] = Are[2];                       // k<64 : Qi
    Aim[1] = Are[3];
    #pragma unroll
    for (int ks = 0; ks < 2; ks++) {       // k>=64: -Qr
        bhalf8 t = Are[ks];
        unsigned* u = (unsigned*)&t;
        #pragma unroll
        for (int j = 0; j < 4; j++) u[j] ^= 0x80008000u;
        Aim[ks + 2] = t;
    }

    f32x4 O[8];
    #pragma unroll
    for (int n = 0; n < 8; n++) O[n] = (f32x4){0.f, 0.f, 0.f, 0.f};
    float Lacc[4] = {0.f, 0.f, 0.f, 0.f};

    int yt0 = (half * 33) / NH, yt1 = ((half + 1) * 33) / NH;

    // ---- per-wave DMA source pointers (bytes) ----
    const char* ksrc = (const char*)Kp
        + ((size_t)bh * NYP + (size_t)yt0 * 32 + w * 8) * 256 + lane * 16;
    const char* vbase = (const char*)Vt + (size_t)bh * 128 * (NYP * 2);
    const char* vsrc0 = vbase + ((size_t)(w * 32) + (lane >> 2)) * (NYP * 2)
                        + (size_t)yt0 * 64 + (lane & 3) * 16;
    const char* vsrc1 = vsrc0 + (size_t)16 * (NYP * 2);

    // swizzled K chunk offsets (ushort units), loop-invariant per lane
    int sw = col & 7;
    int kco[4];
    #pragma unroll
    for (int ks = 0; ks < 4; ks++) kco[ks] = ((ks * 4 + qd) ^ sw) * 8;
    // V chunk unswizzle: stored position of chunk qd in row (n*16+col)
    int vq = (qd ^ ((col >> 2) & 3)) * 8;

    // ---- prologue: stage tile yt0 ----
    {
        int pb = yt0 & 1;
        GLD16(ksrc,         &S.u.kv.Ks[pb][w * 8][0]);
        GLD16(ksrc + 1024,  &S.u.kv.Ks[pb][w * 8 + 4][0]);
        GLD16(vsrc0,        &S.u.kv.Vs[pb][w * 32][0]);
        GLD16(vsrc1,        &S.u.kv.Vs[pb][w * 32 + 16][0]);
        ksrc += 8192; vsrc0 += 64; vsrc1 += 64;
    }

    for (int yt = yt0; yt < yt1; yt++) {
        int cb = yt & 1, nb = cb ^ 1;
        if (yt + 1 < yt1) {
            // issue next tile's DMA (stays in flight across both barriers)
            GLD16(ksrc,         &S.u.kv.Ks[nb][w * 8][0]);
            GLD16(ksrc + 1024,  &S.u.kv.Ks[nb][w * 8 + 4][0]);
            GLD16(vsrc0,        &S.u.kv.Vs[nb][w * 32][0]);
            GLD16(vsrc1,        &S.u.kv.Vs[nb][w * 32 + 16][0]);
            ksrc += 8192; vsrc0 += 64; vsrc1 += 64;
            __builtin_amdgcn_sched_barrier(0);
            asm volatile("s_waitcnt vmcnt(4)" ::: "memory");   // cur tile done
        } else {
            __builtin_amdgcn_sched_barrier(0);
            asm volatile("s_waitcnt vmcnt(0)" ::: "memory");
        }
        __builtin_amdgcn_sched_barrier(0);
        __builtin_amdgcn_s_barrier();                          // all waves' DMA visible
        __builtin_amdgcn_sched_barrier(0);

        const unsigned short* k0 = &S.u.kv.Ks[cb][col][0];
        const unsigned short* k1 = &S.u.kv.Ks[cb][col + 16][0];

        // ---- QK ----
        f32x4 sre[2], sim[2];
        #pragma unroll
        for (int sc = 0; sc < 2; sc++) {
            sre[sc] = (f32x4){0.f, 0.f, 0.f, 0.f};
            sim[sc] = (f32x4){0.f, 0.f, 0.f, 0.f};
        }
        __builtin_amdgcn_s_setprio(1);
        #pragma unroll
        for (int ks = 0; ks < 4; ks++) {
            bhalf8 b0 = *(const bhalf8*)(k0 + kco[ks]);
            bhalf8 b1 = *(const bhalf8*)(k1 + kco[ks]);
            sre[0] = MFMA16(Are[ks], b0, sre[0]);
            sim[0] = MFMA16(Aim[ks], b0, sim[0]);
            sre[1] = MFMA16(Are[ks], b1, sre[1]);
            sim[1] = MFMA16(Aim[ks], b1, sim[1]);
        }
        __builtin_amdgcn_s_setprio(0);

        // ---- p = exp2(sqrt(re^2+im^2))  (0.125*log2e folded into Q) ----
        #pragma unroll
        for (int r = 0; r < 4; r++) {
            float re0 = sre[0][r], im0 = sim[0][r];
            float re1 = sre[1][r], im1 = sim[1][r];
            float s0 = __builtin_amdgcn_sqrtf(fmaf(re0, re0, im0 * im0));
            float s1 = __builtin_amdgcn_sqrtf(fmaf(re1, re1, im1 * im1));
            float p0, p1;
            EXP2F(p0, s0);
            EXP2F(p1, s1);
            Lacc[r] += p0 + p1;
            unsigned up;
            CVTPK(up, p0, p1);
            S.Ps[w][qd * 4 + r][col]      = (unsigned short)up;
            S.Ps[w][qd * 4 + r][col + 16] = (unsigned short)(up >> 16);
        }

        // ---- PV ----
        bhalf8 pa = *(const bhalf8*)&S.Ps[w][col][qd * 8];
        __builtin_amdgcn_s_setprio(1);
        #pragma unroll
        for (int n = 0; n < 8; n++) {
            bhalf8 bv = *(const bhalf8*)&S.u.kv.Vs[cb][n * 16 + col][vq];
            O[n] = MFMA16(pa, bv, O[n]);
        }
        __builtin_amdgcn_s_setprio(0);

        asm volatile("s_waitcnt lgkmcnt(0)" ::: "memory");     // reads retired
        __builtin_amdgcn_sched_barrier(0);
        __builtin_amdgcn_s_barrier();                          // safe to overwrite cb^1
        __builtin_amdgcn_sched_barrier(0);
    }

    // ---- l reduce + store ----
    #pragma unroll
    for (int r = 0; r < 4; r++) {
        float ls = Lacc[r];
        ls += __shfl_xor(ls, 1);
        ls += __shfl_xor(ls, 2);
        ls += __shfl_xor(ls, 4);
        ls += __shfl_xor(ls, 8);
        if (yt1 == 33) ls -= 31.0f;        // zero-pad columns contributed 1 each
        int x = x0 + w * 16 + qd * 4 + r;
        if (x <= 1024 && col == 0)
            lbuf[((size_t)half * 32 + bh) * NYP + x] = ls;
    }

    // ---- numerator: C-layout -> LDS overlay -> coalesced row writes ----
    const size_t HSZ = (size_t)32 * 128 * NYP;
    unsigned short* nplane = (half < 2 ? nb0 : nb1) + (size_t)(half & 1) * HSZ;

    __syncthreads();                       // Ks/Vs dead; safe to overlay
    #pragma unroll
    for (int n = 0; n < 8; n++) {
        unsigned u0, u1;
        CVTPK(u0, O[n][0], O[n][1]);
        CVTPK(u1, O[n][2], O[n][3]);
        *(unsigned*)&S.u.OutT[n * 16 + col][w * 16 + qd * 4]     = u0;
        *(unsigned*)&S.u.OutT[n * 16 + col][w * 16 + qd * 4 + 2] = u1;
    }
    __syncthreads();
    {
        int kk2 = tid >> 1, seg = tid & 1;
        int xg  = x0 + seg * 32;
        if (xg < NYP) {
            unsigned short* dst = nplane + ((size_t)bh * 128 + kk2) * NYP + xg;
            const unsigned short* srcl = &S.u.OutT[kk2][seg * 32];
            #pragma unroll
            for (int m = 0; m < 4; m++)
                *(uint4*)(dst + m * 8) = *(const uint4*)(srcl + m * 8);
        }
    }
}

// ---------------------------------------------------------------------------
// Inverse rFFT (ortho): combine NH partial planes (coalesced bf16 reads),
// packed radix-4 irFFT, write contiguous staging st[bh*64+e][2048] fp32.
// ---------------------------------------------------------------------------
template<int NH>
__global__ __launch_bounds__(256) void fft_inv(const unsigned short* __restrict__ nb0,
                                               const unsigned short* __restrict__ nb1,
                                               const float* __restrict__ lbuf,
                                               float* __restrict__ st)
{
    __shared__ float2 buf[MM];
    __shared__ float2 tw[768];

    int s   = blockIdx.x;          // bh*64 + e
    int e   = s & 63;
    int bh  = s >> 6;
    int tid = threadIdx.x;

    #pragma unroll
    for (int i = tid; i < 768; i += 256) {
        float ang = TWO_PI * (float)i / (float)MM;
        float sv, cv;
        __sincosf(ang, &sv, &cv);
        tw[i] = make_float2(cv, sv);
    }

    const size_t HSZ = (size_t)32 * 128 * NYP;
    const unsigned short* pre[NH];
    const unsigned short* pim[NH];
    const float* lb[NH];
    #pragma unroll
    for (int h = 0; h < NH; h++) {
        const unsigned short* base = (h < 2 ? nb0 : nb1) + (size_t)(h & 1) * HSZ;
        pre[h] = base + ((size_t)bh * 128 + e) * NYP;
        pim[h] = base + ((size_t)bh * 128 + 64 + e) * NYP;
        lb[h]  = lbuf + ((size_t)h * 32 + bh) * NYP;
    }

    #pragma unroll
    for (int i = 0; i < 4; i++) {
        int kk = tid + 256 * i;
        int x1 = kk, x2 = 1024 - kk;
        float d1 = 0.f, d2 = 0.f;
        float Axs = 0.f, Ays = 0.f, Bxs = 0.f, Bys = 0.f;
        #pragma unroll
        for (int h = 0; h < NH; h++) {
            d1 += lb[h][x1];
            d2 += lb[h][x2];
            Axs += bf2f(pre[h][x1]);
            Ays += bf2f(pim[h][x1]);
            Bxs += bf2f(pre[h][x2]);
            Bys += bf2f(pim[h][x2]);
        }
        float iv1 = 1.f / d1, iv2 = 1.f / d2;
        float Ax = Axs * iv1, Ay = Ays * iv1;
        float Bx = Bxs * iv2, By = -(Bys * iv2);
        float Ex = 0.5f * (Ax + Bx), Ey = 0.5f * (Ay + By);
        float Dx = 0.5f * (Ax - Bx), Dy = 0.5f * (Ay - By);
        float th = (TWO_PI / (float)NN) * (float)kk;
        float sn, cs;
        __sincosf(th, &sn, &cs);
        float Ox = Dx * cs - Dy * sn;
        float Oy = Dx * sn + Dy * cs;
        buf[dr4_10((unsigned)kk)] = make_float2(Ex - Oy, Ey + Ox);
    }
    __syncthreads();

    fft_r4_1024<false>(buf, tw, tid);

    float* dst = st + ((size_t)bh * 64 + e) * 2048;
    #pragma unroll
    for (int i = 0; i < 4; i++) {
        int j = tid + 256 * i;
        float2 z = buf[j];
        *(float2*)&dst[2 * j] = make_float2(z.x * INV_SCALE, z.y * INV_SCALE);
    }
}

// ---------------------------------------------------------------------------
// Final transpose: st[bh*64+e][t] -> out[b][t][h][e].  64x64 tiles via LDS.
// ---------------------------------------------------------------------------
__global__ __launch_bounds__(256) void out_tr(const float* __restrict__ st,
                                              float* __restrict__ out)
{
    __shared__ float Ts[64][65];
    int tt  = blockIdx.x;         // t-tile 0..31
    int h   = blockIdx.y;         // 0..7
    int b   = blockIdx.z;         // 0..3
    int tid = threadIdx.x;
    int bh  = b * 8 + h;

    {
        int e = tid >> 2, tc = (tid & 3) * 16;
        const float* src = st + ((size_t)bh * 64 + e) * 2048 + tt * 64 + tc;
        #pragma unroll
        for (int m = 0; m < 4; m++) {
            float4 v4 = *(const float4*)(src + m * 4);
            Ts[e][tc + m * 4 + 0] = v4.x;
            Ts[e][tc + m * 4 + 1] = v4.y;
            Ts[e][tc + m * 4 + 2] = v4.z;
            Ts[e][tc + m * 4 + 3] = v4.w;
        }
    }
    __syncthreads();
    {
        int t = tid >> 2, ec = (tid & 3) * 16;
        float* dst = out + (size_t)b * 2048 * 512 + (size_t)(tt * 64 + t) * 512
                     + h * 64 + ec;
        #pragma unroll
        for (int m = 0; m < 4; m++) {
            float4 v4;
            v4.x = Ts[ec + m * 4 + 0][t];
            v4.y = Ts[ec + m * 4 + 1][t];
            v4.z = Ts[ec + m * 4 + 2][t];
            v4.w = Ts[ec + m * 4 + 3][t];
            *(float4*)(dst + m * 4) = v4;
        }
    }
}

// ---------------------------------------------------------------------------
extern "C" void kernel_launch(void* const* d_in, const int* in_sizes, int n_in,
                              void* d_out, int out_size, void* d_ws, size_t ws_size,
                              hipStream_t stream)
{
    const float* q = (const float*)d_in[0];
    const float* k = (const float*)d_in[1];
    const float* v = (const float*)d_in[2];
    float* out = (float*)d_out;

    char* ws = (char*)d_ws;
    const size_t PL = (size_t)32 * 128 * NYP * sizeof(unsigned short); // 8.65 MB
    unsigned short* Pq = (unsigned short*)(ws);
    unsigned short* Pk = (unsigned short*)(ws + PL);
    unsigned short* Pv = (unsigned short*)(ws + 2 * PL);
    // ttr at 3PL (25.2 MB); dead after fft_fwd, then Qp/Kp reuse the space.
    unsigned short* ttr = (unsigned short*)(ws + 3 * PL);
    unsigned short* Qp = (unsigned short*)(ws + 3 * PL);
    unsigned short* Kp = (unsigned short*)(ws + 4 * PL);
    // st aliases Qp+Kp (dead after flash_mfma): 16.78 MB; ends before 5PL.
    float* st = (float*)(ws + 3 * PL);

    // NH=4 needs: planes 0,1 at [0,2PL) (Pq,Pk dead) + planes 2,3 at
    // [5PL,7PL) + lbuf at 7PL.  Fall back to NH=2 if ws is too small.
    const size_t lbuf4 = (size_t)4 * 32 * NYP * sizeof(float);
    bool big = ws_size >= 7 * PL + lbuf4;

    hipLaunchKernelGGL(tr_fwd, dim3(32, 8, 12), dim3(256), 0, stream,
                       q, k, v, ttr);
    hipLaunchKernelGGL(fft_fwd, dim3(3 * 2048), dim3(256), 0, stream,
                       ttr, Pq, Pk, Pv);
    hipLaunchKernelGGL(qkpack, dim3(33, 32, 2), dim3(256), 0, stream,
                       Pq, Pk, Qp, Kp);

    if (big) {
        unsigned short* nb0 = (unsigned short*)(ws);
        unsigned short* nb1 = (unsigned short*)(ws + 5 * PL);
        float* lbuf = (float*)(ws + 7 * PL);
        hipLaunchKernelGGL((flash_mfma<4>), dim3(17 * 4 * 32), dim3(256), 0, stream,
                           Qp, Kp, Pv, nb0, nb1, lbuf);
        hipLaunchKernelGGL((fft_inv<4>), dim3(2048), dim3(256), 0, stream,
                           nb0, nb1, lbuf, st);
    } else {
        unsigned short* nb0 = (unsigned short*)(ws);
        float* lbuf = (float*)(ws + 5 * PL);
        hipLaunchKernelGGL((flash_mfma<2>), dim3(17 * 2 * 32), dim3(256), 0, stream,
                           Qp, Kp, Pv, nb0, nb0, lbuf);
        hipLaunchKernelGGL((fft_inv<2>), dim3(2048), dim3(256), 0, stream,
                           nb0, nb0, lbuf, st);
    }

    hipLaunchKernelGGL(out_tr, dim3(32, 8, 4), dim3(256), 0, stream,
                       st, out);
}

// Round 6
// 197.747 us; speedup vs baseline: 1.1787x; 1.0481x over previous
//
#include <hip/hip_runtime.h>
#include <hip/hip_bf16.h>
#include <math.h>

// B=4, L=S=2048, H=8, E=64, T=1.0.  I/O fp32.
// Pipeline: mk_tables (twiddle/combine tables in ws) -> tr_fwd (transpose ->
// bf16 [tensor,bh,e][t]) -> fft_fwd (real-packed 1024-pt radix-4 FFT, PADded
// LDS, bf16 planes; Q plane pre-scaled 0.125*log2e; V plane chunk-swizzled)
// -> qkpack (K chunks XOR-swizzled at source for linear-LDS DMA) -> flash_mfma
// (global_load_lds K/V staging, LDS dbuf, counted vmcnt(4), raw s_barrier,
//  setprio, cvt_pk packing, NH=4 y-split) -> fft_inv (padded radix-4) -> out_tr.
// R14: FFT LDS pad PAD(i)=i+(i>>4) — digit-reversed scatter was a 32-way bank
// conflict (all lanes hit one bank-pair); stages 0/1 were 16-way. Now <=4-way.
// Plus precomputed sincos tables (mk_tables) replacing ~1800 __sincosf/block.
#define LOGN  11
#define NN    2048
#define LOGM  10
#define MM    1024
#define NF    1025
#define NYP   1056         // NF padded to 33 tiles of 32 (pads zeroed)
#define TWO_PI 6.283185307179586f
#define INV_SQRT_N 0.022097086912079608f      // 1/sqrt(2048)
#define INV_SCALE  0.044194173824159216f      // 2/sqrt(2048)  (M*z -> out)
#define LOG2E      1.4426950408889634f

#define PAD(i) ((i) + ((i) >> 4))
#define MMP   1088          // PAD(1023)+1
#define TWP   816           // PAD(767)+1

typedef __attribute__((ext_vector_type(8))) short bhalf8;
typedef __attribute__((ext_vector_type(4))) float f32x4;

#define MFMA16(a, b, c) __builtin_amdgcn_mfma_f32_16x16x32_bf16(a, b, c, 0, 0, 0)

#define GLD16(gp, lp)                                                              \
    __builtin_amdgcn_global_load_lds(                                              \
        (const __attribute__((address_space(1))) void*)(gp),                       \
        (__attribute__((address_space(3))) void*)(lp), 16, 0, 0)

#define CVTPK(dst, lo, hi) \
    asm("v_cvt_pk_bf16_f32 %0, %1, %2" : "=v"(dst) : "v"(lo), "v"(hi))

#define EXP2F(dst, src) \
    asm("v_exp_f32 %0, %1" : "=v"(dst) : "v"(src))

__device__ __forceinline__ unsigned short f2bf(float f) {
    union { float f; unsigned u; } v; v.f = f;
    unsigned r = v.u + 0x7FFFu + ((v.u >> 16) & 1u);   // RNE
    return (unsigned short)(r >> 16);
}
__device__ __forceinline__ float bf2f(unsigned short h) {
    union { unsigned u; float f; } v; v.u = ((unsigned)h) << 16;
    return v.f;
}

// base-4 digit reversal of a 10-bit index: pair-swapped bit reversal
__device__ __forceinline__ int dr4_10(unsigned j) {
    unsigned r = __brev(j) >> 22;
    return (int)(((r & 0x155u) << 1) | ((r >> 1) & 0x155u));
}

// ---------------------------------------------------------------------------
// Table setup (once per launch): stage twiddles (fwd = conj) + rFFT combine.
// ---------------------------------------------------------------------------
__global__ __launch_bounds__(256) void mk_tables(float2* __restrict__ twf,
                                                 float2* __restrict__ twi,
                                                 float2* __restrict__ rc)
{
    int i = blockIdx.x * 256 + threadIdx.x;
    if (i < 768) {
        float ang = TWO_PI * (float)i / (float)MM;
        float sv, cv;
        __sincosf(ang, &sv, &cv);
        twf[i] = make_float2(cv, -sv);
        twi[i] = make_float2(cv,  sv);
    }
    if (i < 1025) {
        float ang = TWO_PI * (float)i / (float)NN;
        float sv, cv;
        __sincosf(ang, &sv, &cv);
        rc[i] = make_float2(cv, sv);
    }
}

// ---------------------------------------------------------------------------
// 1024-pt complex radix-4 DIT stages in padded LDS (input digit-reversed,
// stored at PAD()).  tw: PAD-indexed stage twiddles (fwd = conjugated).
// ---------------------------------------------------------------------------
template<bool FWD>
__device__ __forceinline__ void fft_r4_1024(float2* buf, const float2* tw, int tid)
{
    // stage 0 (L=1): twiddles all 1
    {
        int i0 = tid * 4;
        int q0 = PAD(i0), q1 = PAD(i0 + 1), q2 = PAD(i0 + 2), q3 = PAD(i0 + 3);
        float2 a = buf[q0], b = buf[q1], c = buf[q2], d = buf[q3];
        float2 apc = make_float2(a.x + c.x, a.y + c.y);
        float2 amc = make_float2(a.x - c.x, a.y - c.y);
        float2 bpd = make_float2(b.x + d.x, b.y + d.y);
        float2 bmd = make_float2(b.x - d.x, b.y - d.y);
        buf[q0] = make_float2(apc.x + bpd.x, apc.y + bpd.y);
        buf[q2] = make_float2(apc.x - bpd.x, apc.y - bpd.y);
        if (FWD) {
            buf[q1] = make_float2(amc.x + bmd.y, amc.y - bmd.x);
            buf[q3] = make_float2(amc.x - bmd.y, amc.y + bmd.x);
        } else {
            buf[q1] = make_float2(amc.x - bmd.y, amc.y + bmd.x);
            buf[q3] = make_float2(amc.x + bmd.y, amc.y - bmd.x);
        }
        __syncthreads();
    }
    #pragma unroll
    for (int s = 1; s < 5; s++) {
        int L  = 1 << (2 * s);
        int p  = tid & (L - 1);
        int i0 = ((tid >> (2 * s)) << (2 * s + 2)) + p;
        int e  = p << (8 - 2 * s);
        float2 w1 = tw[PAD(e)], w2 = tw[PAD(2 * e)], w3 = tw[PAD(3 * e)];
        int q0 = PAD(i0), q1 = PAD(i0 + L), q2 = PAD(i0 + 2 * L), q3 = PAD(i0 + 3 * L);
        float2 a  = buf[q0];
        float2 xb = buf[q1], xc = buf[q2], xd = buf[q3];
        float2 b = make_float2(xb.x * w1.x - xb.y * w1.y, xb.x * w1.y + xb.y * w1.x);
        float2 c = make_float2(xc.x * w2.x - xc.y * w2.y, xc.x * w2.y + xc.y * w2.x);
        float2 d = make_float2(xd.x * w3.x - xd.y * w3.y, xd.x * w3.y + xd.y * w3.x);
        float2 apc = make_float2(a.x + c.x, a.y + c.y);
        float2 amc = make_float2(a.x - c.x, a.y - c.y);
        float2 bpd = make_float2(b.x + d.x, b.y + d.y);
        float2 bmd = make_float2(b.x - d.x, b.y - d.y);
        buf[q0] = make_float2(apc.x + bpd.x, apc.y + bpd.y);
        buf[q2] = make_float2(apc.x - bpd.x, apc.y - bpd.y);
        if (FWD) {
            buf[q1] = make_float2(amc.x + bmd.y, amc.y - bmd.x);
            buf[q3] = make_float2(amc.x - bmd.y, amc.y + bmd.x);
        } else {
            buf[q1] = make_float2(amc.x - bmd.y, amc.y + bmd.x);
            buf[q3] = make_float2(amc.x + bmd.y, amc.y - bmd.x);
        }
        __syncthreads();
    }
}

// ---------------------------------------------------------------------------
// Input transpose: in[b][t][h][e] fp32 -> ttr[(tensor*32+bh)*64+e][t] bf16.
// 64x64 tiles via LDS; both global sides fully coalesced; packed u32x2 stores.
// ---------------------------------------------------------------------------
__global__ __launch_bounds__(256) void tr_fwd(const float* __restrict__ q,
                                              const float* __restrict__ k,
                                              const float* __restrict__ v,
                                              unsigned short* __restrict__ ttr)
{
    __shared__ float Ts[64][65];
    int tt     = blockIdx.x;          // t-tile 0..31
    int h      = blockIdx.y;          // 0..7
    int z      = blockIdx.z;          // tensor*4 + b
    int tensor = z >> 2;
    int b      = z & 3;
    int tid    = threadIdx.x;
    int t0     = tt * 64;

    const float* in = (tensor == 0) ? q : (tensor == 1) ? k : v;

    {
        int tl = tid >> 2, ec = (tid & 3) * 16;
        const float* src = in + ((size_t)b * 2048 + t0 + tl) * 512 + h * 64 + ec;
        #pragma unroll
        for (int m = 0; m < 4; m++) {
            float4 v4 = *(const float4*)(src + m * 4);
            Ts[tl][ec + m * 4 + 0] = v4.x;
            Ts[tl][ec + m * 4 + 1] = v4.y;
            Ts[tl][ec + m * 4 + 2] = v4.z;
            Ts[tl][ec + m * 4 + 3] = v4.w;
        }
    }
    __syncthreads();
    {
        int el = tid >> 2, tc = (tid & 3) * 16;
        size_t row = ((size_t)(tensor * 32 + b * 8 + h)) * 64 + el;
        unsigned short* dst = ttr + row * 2048 + t0 + tc;
        #pragma unroll
        for (int m = 0; m < 4; m++) {
            float a0 = Ts[tc + m * 4 + 0][el], a1 = Ts[tc + m * 4 + 1][el];
            float a2 = Ts[tc + m * 4 + 2][el], a3 = Ts[tc + m * 4 + 3][el];
            unsigned u0, u1;
            CVTPK(u0, a0, a1);
            CVTPK(u1, a2, a3);
            uint2 o; o.x = u0; o.y = u1;
            *(uint2*)(dst + m * 4) = o;
        }
    }
}

// ---------------------------------------------------------------------------
// Forward rFFT (ortho) via real-packing, reading contiguous bf16 series.
// Output bf16 planes P[bh*128+kk][1056]; Q plane carries 0.125*log2e.
// V plane: 8-elem chunks stored at chunk ^ ((row>>2)&3) (block-uniform) for
// conflict-free flash PV reads.  Grid: g = e*96 + (tensor*32+bh).
// ---------------------------------------------------------------------------
__global__ __launch_bounds__(256) void fft_fwd(const unsigned short* __restrict__ ttr,
                                               const float2* __restrict__ twg,
                                               const float2* __restrict__ rc,
                                               unsigned short* __restrict__ Pq,
                                               unsigned short* __restrict__ Pk,
                                               unsigned short* __restrict__ Pv)
{
    __shared__ float2 buf[MMP];
    __shared__ float2 tw[TWP];

    int g      = blockIdx.x;
    int p      = g % 96;              // tensor*32 + bh
    int e      = g / 96;              // 0..63
    int tensor = p / 32;
    int bh     = p % 32;
    int tid    = threadIdx.x;

    unsigned short* plane = (tensor == 0) ? Pq : (tensor == 1) ? Pk : Pv;
    float scl = (tensor == 0) ? (INV_SQRT_N * 0.125f * LOG2E) : INV_SQRT_N;
    int vk3 = (tensor == 2) ? (((e >> 2) & 3) << 3) : 0;   // V chunk swizzle

    #pragma unroll
    for (int i = tid; i < 768; i += 256) tw[PAD(i)] = twg[i];

    const unsigned short* src = ttr + ((size_t)p * 64 + e) * 2048;
    #pragma unroll
    for (int i = 0; i < 4; i++) {
        int j = tid + 256 * i;
        unsigned pr = *(const unsigned*)(src + 2 * j);   // x[2j], x[2j+1]
        float x0 = bf2f((unsigned short)(pr & 0xFFFFu));
        float x1 = bf2f((unsigned short)(pr >> 16));
        buf[PAD(dr4_10((unsigned)j))] = make_float2(x0, x1);
    }
    __syncthreads();

    fft_r4_1024<true>(buf, tw, tid);

    unsigned short* dre = plane + ((size_t)bh * 128 + e) * NYP;
    unsigned short* dim_ = dre + (size_t)64 * NYP;

    // fwd combine uses (cs,sn) = (rc.x, -rc.y):
    //   XR = Ex + cx*Ox + cy*Oy ;  XI = Ey + cx*Oy - cy*Ox
#define RPOINT(Ai, Bi, CX, CY, XR, XI) do {                                \
        float Ex = 0.5f * (Ai.x + Bi.x), Ey = 0.5f * (Ai.y - Bi.y);        \
        float Dx = 0.5f * (Ai.x - Bi.x), Dy = 0.5f * (Ai.y + Bi.y);        \
        float Ox = Dy, Oy = -Dx;                                           \
        XR = (Ex + (CX) * Ox + (CY) * Oy) * scl;                           \
        XI = (Ey + (CX) * Oy - (CY) * Ox) * scl;                           \
    } while (0)

    #pragma unroll
    for (int i = 0; i < 2; i++) {
        int kk = 2 * tid + 512 * i;                  // even, 0..1022
        float2 A0 = buf[PAD(kk)];
        float2 B0 = buf[PAD((MM - kk) & (MM - 1))];
        float2 A1 = buf[PAD(kk + 1)];
        float2 B1 = buf[PAD(MM - kk - 1)];
        float4 rq = *(const float4*)(&rc[kk]);       // (c0,s0,c1,s1)
        float Xr0, Xi0, Xr1, Xi1;
        RPOINT(A0, B0, rq.x, rq.y, Xr0, Xi0);
        RPOINT(A1, B1, rq.z, rq.w, Xr1, Xi1);
        unsigned ur, ui;
        CVTPK(ur, Xr0, Xr1);
        CVTPK(ui, Xi0, Xi1);
        int ks = kk ^ vk3;                           // swizzle stays even
        *(unsigned*)(dre + ks)  = ur;
        *(unsigned*)(dim_ + ks) = ui;
    }
    // tail: kk = 1024 (cs=-1, sn=0) + zero pads 1025..1055, as 16 u32 stores
    if (tid < 16) {
        unsigned ur = 0, ui = 0;
        if (tid == 0) {
            float2 A = buf[PAD(0)];                   // A == Bc at kk=1024
            float Xr = (A.x - A.y) * scl;             // Ex + (-1)*Ox
            float zz = 0.f;
            CVTPK(ur, Xr, zz);
        }
        int ks = (1024 + 2 * tid) ^ vk3;
        *(unsigned*)(dre + ks)  = ur;
        *(unsigned*)(dim_ + ks) = ui;
    }
#undef RPOINT
}

// ---------------------------------------------------------------------------
// Transpose q,k planes [bh*128+kk][1056] -> [bh][1056][128].
// K rows are written with 16B chunks XOR-swizzled (chunk ^ (y&7)) so flash can
// DMA them linearly into LDS and still read bank-conflict-free (rule #21).
// ---------------------------------------------------------------------------
__global__ __launch_bounds__(256) void qkpack(const unsigned short* __restrict__ Pq,
                                              const unsigned short* __restrict__ Pk,
                                              unsigned short* __restrict__ Qp,
                                              unsigned short* __restrict__ Kp)
{
    __shared__ unsigned short Ts[32][136];
    int y0  = blockIdx.x * 32;
    int bh  = blockIdx.y;
    int tsr = blockIdx.z;
    int tid = threadIdx.x;

    const unsigned short* srcp = (tsr == 0) ? Pq : Pk;
    unsigned short* dstp       = (tsr == 0) ? Qp : Kp;

    {
        int kk = tid >> 1, seg = tid & 1;
        const unsigned short* sp = srcp + ((size_t)bh * 128 + kk) * NYP + y0 + seg * 16;
        uint4 va = *(const uint4*)sp;
        uint4 vb = *(const uint4*)(sp + 8);
        const unsigned short* pa = (const unsigned short*)&va;
        const unsigned short* pb = (const unsigned short*)&vb;
        #pragma unroll
        for (int j = 0; j < 8; j++) Ts[seg * 16 + j][kk] = pa[j];
        #pragma unroll
        for (int j = 0; j < 8; j++) Ts[seg * 16 + 8 + j][kk] = pb[j];
    }
    __syncthreads();
    {
        int y = tid >> 3, c = tid & 7;       // c: 32B pair (chunks 2c, 2c+1)
        uint4 lo = *(const uint4*)&Ts[y][c * 16];
        uint4 hi = *(const uint4*)&Ts[y][c * 16 + 8];
        char* rowb = (char*)(dstp + ((size_t)bh * NYP + y0 + y) * 128);
        if (tsr == 0) {
            *(uint4*)(rowb + c * 32)      = lo;
            *(uint4*)(rowb + c * 32 + 16) = hi;
        } else {
            int s = y & 7;
            *(uint4*)(rowb + (((2 * c)     ^ s) << 4)) = lo;
            *(uint4*)(rowb + (((2 * c + 1) ^ s) << 4)) = hi;
        }
    }
}

// ---------------------------------------------------------------------------
// MFMA flash attention, no-max softmax, y-split xNH, XCD swizzle.
// K/V staged via global_load_lds into LDS double-buffer; counted vmcnt(4)
// keeps next-tile loads in flight across raw s_barriers (T3/T4); setprio (T5).
// numb partial planes: [h][bh][kk=0..127][x=0..1055] bf16; planes 0,1 at nb0,
// planes 2,3 at nb1 (two disjoint ws regions).
// ---------------------------------------------------------------------------
struct FlashShared {
    union {
        struct {
            unsigned short Ks[2][32][128];   // 16 KB, chunk-XOR-swizzled rows
            unsigned short Vs[2][128][32];   // 16 KB, chunk-swizzled (fft_fwd)
        } kv;                                // 32 KB
        unsigned short OutT[128][72];        // 18 KB (epilogue only)
    } u;
    unsigned short Ps[4][16][40];            // 5 KB, wave-private
};

template<int NH>
__global__ __launch_bounds__(256) void flash_mfma(
    const unsigned short* __restrict__ Qp,   // [bh][1056][128] bf16 (scaled)
    const unsigned short* __restrict__ Kp,   // [bh][1056][128] bf16, swizzled
    const unsigned short* __restrict__ Vt,   // [bh*128+kk][1056] bf16, swizzled
    unsigned short* __restrict__ nb0,        // partial planes 0,1
    unsigned short* __restrict__ nb1,        // partial planes 2,3 (NH=4)
    float* __restrict__ lbuf)                // [NH][bh*1056+x] fp32
{
    __shared__ FlashShared S;

    int g    = blockIdx.x;            // idx*32 + bh : g%8 == bh%8 (XCD pin)
    int bh   = g & 31;
    int idx  = g >> 5;                // 0..17*NH-1
    int half = idx / 17;              // y-quarter (or y-half)
    int x0   = (idx % 17) * 64;
    int tid  = threadIdx.x;
    int w    = tid >> 6;
    int lane = tid & 63;
    int qd   = lane >> 4;
    int col  = lane & 15;

    // ---- Q A-fragments: direct bf16 loads + sign trick ----
    int xrow = x0 + w * 16 + col;
    int xq   = min(xrow, 1024);
    const unsigned short* qb = Qp + ((size_t)bh * NYP + xq) * 128 + qd * 8;
    bhalf8 Are[4], Aim[4];
    #pragma unroll
    for (int ks = 0; ks < 4; ks++) Are[ks] = *(const bhalf8*)(qb + ks * 32);
    Aim[0] = Are[2];                       // k<64 : Qi
    Aim[1] = Are[3];
    #pragma unroll
    for (int ks = 0; ks < 2; ks++) {       // k>=64: -Qr
        bhalf8 t = Are[ks];
        unsigned* u = (unsigned*)&t;
        #pragma unroll
        for (int j = 0; j < 4; j++) u[j] ^= 0x80008000u;
        Aim[ks + 2] = t;
    }

    f32x4 O[8];
    #pragma unroll
    for (int n = 0; n < 8; n++) O[n] = (f32x4){0.f, 0.f, 0.f, 0.f};
    float Lacc[4] = {0.f, 0.f, 0.f, 0.f};

    int yt0 = (half * 33) / NH, yt1 = ((half + 1) * 33) / NH;

    // ---- per-wave DMA source pointers (bytes) ----
    const char* ksrc = (const char*)Kp
        + ((size_t)bh * NYP + (size_t)yt0 * 32 + w * 8) * 256 + lane * 16;
    const char* vbase = (const char*)Vt + (size_t)bh * 128 * (NYP * 2);
    const char* vsrc0 = vbase + ((size_t)(w * 32) + (lane >> 2)) * (NYP * 2)
                        + (size_t)yt0 * 64 + (lane & 3) * 16;
    const char* vsrc1 = vsrc0 + (size_t)16 * (NYP * 2);

    // swizzled K chunk offsets (ushort units), loop-invariant per lane
    int sw = col & 7;
    int kco[4];
    #pragma unroll
    for (int ks = 0; ks < 4; ks++) kco[ks] = ((ks * 4 + qd) ^ sw) * 8;
    // V chunk unswizzle: stored position of chunk qd in row (n*16+col)
    int vq = (qd ^ ((col >> 2) & 3)) * 8;

    // ---- prologue: stage tile yt0 ----
    {
        int pb = yt0 & 1;
        GLD16(ksrc,         &S.u.kv.Ks[pb][w * 8][0]);
        GLD16(ksrc + 1024,  &S.u.kv.Ks[pb][w * 8 + 4][0]);
        GLD16(vsrc0,        &S.u.kv.Vs[pb][w * 32][0]);
        GLD16(vsrc1,        &S.u.kv.Vs[pb][w * 32 + 16][0]);
        ksrc += 8192; vsrc0 += 64; vsrc1 += 64;
    }

    for (int yt = yt0; yt < yt1; yt++) {
        int cb = yt & 1, nb = cb ^ 1;
        if (yt + 1 < yt1) {
            // issue next tile's DMA (stays in flight across both barriers)
            GLD16(ksrc,         &S.u.kv.Ks[nb][w * 8][0]);
            GLD16(ksrc + 1024,  &S.u.kv.Ks[nb][w * 8 + 4][0]);
            GLD16(vsrc0,        &S.u.kv.Vs[nb][w * 32][0]);
            GLD16(vsrc1,        &S.u.kv.Vs[nb][w * 32 + 16][0]);
            ksrc += 8192; vsrc0 += 64; vsrc1 += 64;
            __builtin_amdgcn_sched_barrier(0);
            asm volatile("s_waitcnt vmcnt(4)" ::: "memory");   // cur tile done
        } else {
            __builtin_amdgcn_sched_barrier(0);
            asm volatile("s_waitcnt vmcnt(0)" ::: "memory");
        }
        __builtin_amdgcn_sched_barrier(0);
        __builtin_amdgcn_s_barrier();                          // all waves' DMA visible
        __builtin_amdgcn_sched_barrier(0);

        const unsigned short* k0 = &S.u.kv.Ks[cb][col][0];
        const unsigned short* k1 = &S.u.kv.Ks[cb][col + 16][0];

        // ---- QK ----
        f32x4 sre[2], sim[2];
        #pragma unroll
        for (int sc = 0; sc < 2; sc++) {
            sre[sc] = (f32x4){0.f, 0.f, 0.f, 0.f};
            sim[sc] = (f32x4){0.f, 0.f, 0.f, 0.f};
        }
        __builtin_amdgcn_s_setprio(1);
        #pragma unroll
        for (int ks = 0; ks < 4; ks++) {
            bhalf8 b0 = *(const bhalf8*)(k0 + kco[ks]);
            bhalf8 b1 = *(const bhalf8*)(k1 + kco[ks]);
            sre[0] = MFMA16(Are[ks], b0, sre[0]);
            sim[0] = MFMA16(Aim[ks], b0, sim[0]);
            sre[1] = MFMA16(Are[ks], b1, sre[1]);
            sim[1] = MFMA16(Aim[ks], b1, sim[1]);
        }
        __builtin_amdgcn_s_setprio(0);

        // ---- p = exp2(sqrt(re^2+im^2))  (0.125*log2e folded into Q) ----
        #pragma unroll
        for (int r = 0; r < 4; r++) {
            float re0 = sre[0][r], im0 = sim[0][r];
            float re1 = sre[1][r], im1 = sim[1][r];
            float s0 = __builtin_amdgcn_sqrtf(fmaf(re0, re0, im0 * im0));
            float s1 = __builtin_amdgcn_sqrtf(fmaf(re1, re1, im1 * im1));
            float p0, p1;
            EXP2F(p0, s0);
            EXP2F(p1, s1);
            Lacc[r] += p0 + p1;
            unsigned up;
            CVTPK(up, p0, p1);
            S.Ps[w][qd * 4 + r][col]      = (unsigned short)up;
            S.Ps[w][qd * 4 + r][col + 16] = (unsigned short)(up >> 16);
        }

        // ---- PV ----
        bhalf8 pa = *(const bhalf8*)&S.Ps[w][col][qd * 8];
        __builtin_amdgcn_s_setprio(1);
        #pragma unroll
        for (int n = 0; n < 8; n++) {
            bhalf8 bv = *(const bhalf8*)&S.u.kv.Vs[cb][n * 16 + col][vq];
            O[n] = MFMA16(pa, bv, O[n]);
        }
        __builtin_amdgcn_s_setprio(0);

        asm volatile("s_waitcnt lgkmcnt(0)" ::: "memory");     // reads retired
        __builtin_amdgcn_sched_barrier(0);
        __builtin_amdgcn_s_barrier();                          // safe to overwrite cb^1
        __builtin_amdgcn_sched_barrier(0);
    }

    // ---- l reduce + store ----
    #pragma unroll
    for (int r = 0; r < 4; r++) {
        float ls = Lacc[r];
        ls += __shfl_xor(ls, 1);
        ls += __shfl_xor(ls, 2);
        ls += __shfl_xor(ls, 4);
        ls += __shfl_xor(ls, 8);
        if (yt1 == 33) ls -= 31.0f;        // zero-pad columns contributed 1 each
        int x = x0 + w * 16 + qd * 4 + r;
        if (x <= 1024 && col == 0)
            lbuf[((size_t)half * 32 + bh) * NYP + x] = ls;
    }

    // ---- numerator: C-layout -> LDS overlay -> coalesced row writes ----
    const size_t HSZ = (size_t)32 * 128 * NYP;
    unsigned short* nplane = (half < 2 ? nb0 : nb1) + (size_t)(half & 1) * HSZ;

    __syncthreads();                       // Ks/Vs dead; safe to overlay
    #pragma unroll
    for (int n = 0; n < 8; n++) {
        unsigned u0, u1;
        CVTPK(u0, O[n][0], O[n][1]);
        CVTPK(u1, O[n][2], O[n][3]);
        *(unsigned*)&S.u.OutT[n * 16 + col][w * 16 + qd * 4]     = u0;
        *(unsigned*)&S.u.OutT[n * 16 + col][w * 16 + qd * 4 + 2] = u1;
    }
    __syncthreads();
    {
        int kk2 = tid >> 1, seg = tid & 1;
        int xg  = x0 + seg * 32;
        if (xg < NYP) {
            unsigned short* dst = nplane + ((size_t)bh * 128 + kk2) * NYP + xg;
            const unsigned short* srcl = &S.u.OutT[kk2][seg * 32];
            #pragma unroll
            for (int m = 0; m < 4; m++)
                *(uint4*)(dst + m * 8) = *(const uint4*)(srcl + m * 8);
        }
    }
}

// ---------------------------------------------------------------------------
// Inverse rFFT (ortho): combine NH partial planes (coalesced bf16 reads),
// packed padded radix-4 irFFT, write contiguous staging st[bh*64+e][2048] fp32.
// ---------------------------------------------------------------------------
template<int NH>
__global__ __launch_bounds__(256) void fft_inv(const unsigned short* __restrict__ nb0,
                                               const unsigned short* __restrict__ nb1,
                                               const float2* __restrict__ twg,
                                               const float2* __restrict__ rc,
                                               const float* __restrict__ lbuf,
                                               float* __restrict__ st)
{
    __shared__ float2 buf[MMP];
    __shared__ float2 tw[TWP];

    int s   = blockIdx.x;          // bh*64 + e
    int e   = s & 63;
    int bh  = s >> 6;
    int tid = threadIdx.x;

    #pragma unroll
    for (int i = tid; i < 768; i += 256) tw[PAD(i)] = twg[i];

    const size_t HSZ = (size_t)32 * 128 * NYP;
    const unsigned short* pre[NH];
    const unsigned short* pim[NH];
    const float* lb[NH];
    #pragma unroll
    for (int h = 0; h < NH; h++) {
        const unsigned short* base = (h < 2 ? nb0 : nb1) + (size_t)(h & 1) * HSZ;
        pre[h] = base + ((size_t)bh * 128 + e) * NYP;
        pim[h] = base + ((size_t)bh * 128 + 64 + e) * NYP;
        lb[h]  = lbuf + ((size_t)h * 32 + bh) * NYP;
    }

    #pragma unroll
    for (int i = 0; i < 4; i++) {
        int kk = tid + 256 * i;
        int x1 = kk, x2 = 1024 - kk;
        float d1 = 0.f, d2 = 0.f;
        float Axs = 0.f, Ays = 0.f, Bxs = 0.f, Bys = 0.f;
        #pragma unroll
        for (int h = 0; h < NH; h++) {
            d1 += lb[h][x1];
            d2 += lb[h][x2];
            Axs += bf2f(pre[h][x1]);
            Ays += bf2f(pim[h][x1]);
            Bxs += bf2f(pre[h][x2]);
            Bys += bf2f(pim[h][x2]);
        }
        float iv1 = 1.f / d1, iv2 = 1.f / d2;
        float Ax = Axs * iv1, Ay = Ays * iv1;
        float Bx = Bxs * iv2, By = -(Bys * iv2);
        float Ex = 0.5f * (Ax + Bx), Ey = 0.5f * (Ay + By);
        float Dx = 0.5f * (Ax - Bx), Dy = 0.5f * (Ay - By);
        float2 rcv = rc[kk];                 // (cos, sin) of +2*pi*kk/2048
        float Ox = Dx * rcv.x - Dy * rcv.y;
        float Oy = Dx * rcv.y + Dy * rcv.x;
        buf[PAD(dr4_10((unsigned)kk))] = make_float2(Ex - Oy, Ey + Ox);
    }
    __syncthreads();

    fft_r4_1024<false>(buf, tw, tid);

    float* dst = st + ((size_t)bh * 64 + e) * 2048;
    #pragma unroll
    for (int i = 0; i < 4; i++) {
        int j = tid + 256 * i;
        float2 z = buf[PAD(j)];
        *(float2*)&dst[2 * j] = make_float2(z.x * INV_SCALE, z.y * INV_SCALE);
    }
}

// ---------------------------------------------------------------------------
// Final transpose: st[bh*64+e][t] -> out[b][t][h][e].  64x64 tiles via LDS.
// ---------------------------------------------------------------------------
__global__ __launch_bounds__(256) void out_tr(const float* __restrict__ st,
                                              float* __restrict__ out)
{
    __shared__ float Ts[64][65];
    int tt  = blockIdx.x;         // t-tile 0..31
    int h   = blockIdx.y;         // 0..7
    int b   = blockIdx.z;         // 0..3
    int tid = threadIdx.x;
    int bh  = b * 8 + h;

    {
        int e = tid >> 2, tc = (tid & 3) * 16;
        const float* src = st + ((size_t)bh * 64 + e) * 2048 + tt * 64 + tc;
        #pragma unroll
        for (int m = 0; m < 4; m++) {
            float4 v4 = *(const float4*)(src + m * 4);
            Ts[e][tc + m * 4 + 0] = v4.x;
            Ts[e][tc + m * 4 + 1] = v4.y;
            Ts[e][tc + m * 4 + 2] = v4.z;
            Ts[e][tc + m * 4 + 3] = v4.w;
        }
    }
    __syncthreads();
    {
        int t = tid >> 2, ec = (tid & 3) * 16;
        float* dst = out + (size_t)b * 2048 * 512 + (size_t)(tt * 64 + t) * 512
                     + h * 64 + ec;
        #pragma unroll
        for (int m = 0; m < 4; m++) {
            float4 v4;
            v4.x = Ts[ec + m * 4 + 0][t];
            v4.y = Ts[ec + m * 4 + 1][t];
            v4.z = Ts[ec + m * 4 + 2][t];
            v4.w = Ts[ec + m * 4 + 3][t];
            *(float4*)(dst + m * 4) = v4;
        }
    }
}

// ---------------------------------------------------------------------------
extern "C" void kernel_launch(void* const* d_in, const int* in_sizes, int n_in,
                              void* d_out, int out_size, void* d_ws, size_t ws_size,
                              hipStream_t stream)
{
    const float* q = (const float*)d_in[0];
    const float* k = (const float*)d_in[1];
    const float* v = (const float*)d_in[2];
    float* out = (float*)d_out;

    char* ws = (char*)d_ws;
    const size_t PL = (size_t)32 * 128 * NYP * sizeof(unsigned short); // 8.65 MB
    unsigned short* Pq = (unsigned short*)(ws);
    unsigned short* Pk = (unsigned short*)(ws + PL);
    unsigned short* Pv = (unsigned short*)(ws + 2 * PL);
    // ttr at 3PL (25.2 MB); dead after fft_fwd, then Qp/Kp reuse the space.
    unsigned short* ttr = (unsigned short*)(ws + 3 * PL);
    unsigned short* Qp = (unsigned short*)(ws + 3 * PL);
    unsigned short* Kp = (unsigned short*)(ws + 4 * PL);
    // st aliases Qp+Kp (dead after flash_mfma): 16.78 MB; ends before 5PL.
    float* st = (float*)(ws + 3 * PL);

    const size_t lbuf4 = (size_t)4 * 32 * NYP * sizeof(float);
    const size_t lbuf2 = (size_t)2 * 32 * NYP * sizeof(float);
    const size_t TBL   = (size_t)(768 + 768 + 1025) * sizeof(float2);  // 20.5 KB
    bool big = ws_size >= 7 * PL + lbuf4 + TBL;

    // tables live past every live region in both paths
    char* tb = big ? (ws + 7 * PL + lbuf4) : (ws + 5 * PL + lbuf2);
    float2* twf = (float2*)tb;
    float2* twi = twf + 768;
    float2* rc  = twi + 768;

    hipLaunchKernelGGL(mk_tables, dim3(5), dim3(256), 0, stream, twf, twi, rc);
    hipLaunchKernelGGL(tr_fwd, dim3(32, 8, 12), dim3(256), 0, stream,
                       q, k, v, ttr);
    hipLaunchKernelGGL(fft_fwd, dim3(3 * 2048), dim3(256), 0, stream,
                       ttr, twf, rc, Pq, Pk, Pv);
    hipLaunchKernelGGL(qkpack, dim3(33, 32, 2), dim3(256), 0, stream,
                       Pq, Pk, Qp, Kp);

    if (big) {
        unsigned short* nb0 = (unsigned short*)(ws);
        unsigned short* nb1 = (unsigned short*)(ws + 5 * PL);
        float* lbuf = (float*)(ws + 7 * PL);
        hipLaunchKernelGGL((flash_mfma<4>), dim3(17 * 4 * 32), dim3(256), 0, stream,
                           Qp, Kp, Pv, nb0, nb1, lbuf);
        hipLaunchKernelGGL((fft_inv<4>), dim3(2048), dim3(256), 0, stream,
                           nb0, nb1, twi, rc, lbuf, st);
    } else {
        unsigned short* nb0 = (unsigned short*)(ws);
        float* lbuf = (float*)(ws + 5 * PL);
        hipLaunchKernelGGL((flash_mfma<2>), dim3(17 * 2 * 32), dim3(256), 0, stream,
                           Qp, Kp, Pv, nb0, nb0, lbuf);
        hipLaunchKernelGGL((fft_inv<2>), dim3(2048), dim3(256), 0, stream,
                           nb0, nb0, twi, rc, lbuf, st);
    }

    hipLaunchKernelGGL(out_tr, dim3(32, 8, 4), dim3(256), 0, stream,
                       st, out);
}

// Round 7
// 197.103 us; speedup vs baseline: 1.1826x; 1.0033x over previous
//
#include <hip/hip_runtime.h>
#include <hip/hip_bf16.h>
#include <math.h>

// B=4, L=S=2048, H=8, E=64, T=1.0.  I/O fp32.
// Pipeline: tr_fwd (transpose -> bf16 [tensor,bh,e][t]; first 5 blocks also
// build twiddle/combine tables in ws) -> fft_fwd (real-packed 1024-pt radix-4
// FFT, 2 series/block, PADded LDS; Q plane pre-scaled 0.125*log2e; V plane
// chunk-swizzled) -> qkpack (K chunks XOR-swizzled for linear-LDS DMA)
// -> flash_mfma (global_load_lds K/V staging, LDS dbuf, counted vmcnt(4),
//  raw s_barrier, setprio, cvt_pk, NH=4 y-split) -> fft_inv (2 series/block,
//  shared denominators) -> out_tr.
// R15: FFT kernels were barrier-bound (1 butterfly/thread/stage between full
// drains). Batch 2 series per block: half the barriers per series, shared
// twiddles, shared l-denominators in fft_inv; mk_tables folded into tr_fwd.
#define LOGN  11
#define NN    2048
#define LOGM  10
#define MM    1024
#define NF    1025
#define NYP   1056         // NF padded to 33 tiles of 32 (pads zeroed)
#define TWO_PI 6.283185307179586f
#define INV_SQRT_N 0.022097086912079608f      // 1/sqrt(2048)
#define INV_SCALE  0.044194173824159216f      // 2/sqrt(2048)  (M*z -> out)
#define LOG2E      1.4426950408889634f

#define PAD(i) ((i) + ((i) >> 4))
#define MMP   1088          // PAD(1023)+1
#define TWP   816           // PAD(767)+1

typedef __attribute__((ext_vector_type(8))) short bhalf8;
typedef __attribute__((ext_vector_type(4))) float f32x4;

#define MFMA16(a, b, c) __builtin_amdgcn_mfma_f32_16x16x32_bf16(a, b, c, 0, 0, 0)

#define GLD16(gp, lp)                                                              \
    __builtin_amdgcn_global_load_lds(                                              \
        (const __attribute__((address_space(1))) void*)(gp),                       \
        (__attribute__((address_space(3))) void*)(lp), 16, 0, 0)

#define CVTPK(dst, lo, hi) \
    asm("v_cvt_pk_bf16_f32 %0, %1, %2" : "=v"(dst) : "v"(lo), "v"(hi))

#define EXP2F(dst, src) \
    asm("v_exp_f32 %0, %1" : "=v"(dst) : "v"(src))

__device__ __forceinline__ unsigned short f2bf(float f) {
    union { float f; unsigned u; } v; v.f = f;
    unsigned r = v.u + 0x7FFFu + ((v.u >> 16) & 1u);   // RNE
    return (unsigned short)(r >> 16);
}
__device__ __forceinline__ float bf2f(unsigned short h) {
    union { unsigned u; float f; } v; v.u = ((unsigned)h) << 16;
    return v.f;
}

// base-4 digit reversal of a 10-bit index: pair-swapped bit reversal
__device__ __forceinline__ int dr4_10(unsigned j) {
    unsigned r = __brev(j) >> 22;
    return (int)(((r & 0x155u) << 1) | ((r >> 1) & 0x155u));
}

// ---------------------------------------------------------------------------
// 1024-pt complex radix-4 DIT stages in padded LDS, 2 series at once.
// tw: PAD-indexed stage twiddles (fwd = conjugated).
// ---------------------------------------------------------------------------
template<bool FWD>
__device__ __forceinline__ void fft_r4_1024x2(float2 buf[2][MMP],
                                              const float2* tw, int tid)
{
    // stage 0 (L=1): twiddles all 1
    {
        int i0 = tid * 4;
        int q0 = PAD(i0), q1 = PAD(i0 + 1), q2 = PAD(i0 + 2), q3 = PAD(i0 + 3);
        #pragma unroll
        for (int b2 = 0; b2 < 2; b2++) {
            float2 a = buf[b2][q0], b = buf[b2][q1], c = buf[b2][q2], d = buf[b2][q3];
            float2 apc = make_float2(a.x + c.x, a.y + c.y);
            float2 amc = make_float2(a.x - c.x, a.y - c.y);
            float2 bpd = make_float2(b.x + d.x, b.y + d.y);
            float2 bmd = make_float2(b.x - d.x, b.y - d.y);
            buf[b2][q0] = make_float2(apc.x + bpd.x, apc.y + bpd.y);
            buf[b2][q2] = make_float2(apc.x - bpd.x, apc.y - bpd.y);
            if (FWD) {
                buf[b2][q1] = make_float2(amc.x + bmd.y, amc.y - bmd.x);
                buf[b2][q3] = make_float2(amc.x - bmd.y, amc.y + bmd.x);
            } else {
                buf[b2][q1] = make_float2(amc.x - bmd.y, amc.y + bmd.x);
                buf[b2][q3] = make_float2(amc.x + bmd.y, amc.y - bmd.x);
            }
        }
        __syncthreads();
    }
    #pragma unroll
    for (int s = 1; s < 5; s++) {
        int L  = 1 << (2 * s);
        int p  = tid & (L - 1);
        int i0 = ((tid >> (2 * s)) << (2 * s + 2)) + p;
        int e  = p << (8 - 2 * s);
        float2 w1 = tw[PAD(e)], w2 = tw[PAD(2 * e)], w3 = tw[PAD(3 * e)];
        int q0 = PAD(i0), q1 = PAD(i0 + L), q2 = PAD(i0 + 2 * L), q3 = PAD(i0 + 3 * L);
        #pragma unroll
        for (int b2 = 0; b2 < 2; b2++) {
            float2 a  = buf[b2][q0];
            float2 xb = buf[b2][q1], xc = buf[b2][q2], xd = buf[b2][q3];
            float2 b = make_float2(xb.x * w1.x - xb.y * w1.y, xb.x * w1.y + xb.y * w1.x);
            float2 c = make_float2(xc.x * w2.x - xc.y * w2.y, xc.x * w2.y + xc.y * w2.x);
            float2 d = make_float2(xd.x * w3.x - xd.y * w3.y, xd.x * w3.y + xd.y * w3.x);
            float2 apc = make_float2(a.x + c.x, a.y + c.y);
            float2 amc = make_float2(a.x - c.x, a.y - c.y);
            float2 bpd = make_float2(b.x + d.x, b.y + d.y);
            float2 bmd = make_float2(b.x - d.x, b.y - d.y);
            buf[b2][q0] = make_float2(apc.x + bpd.x, apc.y + bpd.y);
            buf[b2][q2] = make_float2(apc.x - bpd.x, apc.y - bpd.y);
            if (FWD) {
                buf[b2][q1] = make_float2(amc.x + bmd.y, amc.y - bmd.x);
                buf[b2][q3] = make_float2(amc.x - bmd.y, amc.y + bmd.x);
            } else {
                buf[b2][q1] = make_float2(amc.x - bmd.y, amc.y + bmd.x);
                buf[b2][q3] = make_float2(amc.x + bmd.y, amc.y - bmd.x);
            }
        }
        __syncthreads();
    }
}

// ---------------------------------------------------------------------------
// Input transpose: in[b][t][h][e] fp32 -> ttr[(tensor*32+bh)*64+e][t] bf16.
// 64x64 tiles via LDS; both global sides fully coalesced; packed u32x2 stores.
// First 5 (y==0,z==0) blocks also build the twiddle/combine tables.
// ---------------------------------------------------------------------------
__global__ __launch_bounds__(256) void tr_fwd(const float* __restrict__ q,
                                              const float* __restrict__ k,
                                              const float* __restrict__ v,
                                              unsigned short* __restrict__ ttr,
                                              float2* __restrict__ twf,
                                              float2* __restrict__ twi,
                                              float2* __restrict__ rc)
{
    __shared__ float Ts[64][65];
    int tt     = blockIdx.x;          // t-tile 0..31
    int h      = blockIdx.y;          // 0..7
    int z      = blockIdx.z;          // tensor*4 + b
    int tensor = z >> 2;
    int b      = z & 3;
    int tid    = threadIdx.x;
    int t0     = tt * 64;

    if (z == 0 && h == 0 && tt < 5) {          // table gen (once per launch)
        int i = tt * 256 + tid;
        if (i < 768) {
            float ang = TWO_PI * (float)i / (float)MM;
            float sv, cv;
            __sincosf(ang, &sv, &cv);
            twf[i] = make_float2(cv, -sv);
            twi[i] = make_float2(cv,  sv);
        }
        if (i < 1025) {
            float ang = TWO_PI * (float)i / (float)NN;
            float sv, cv;
            __sincosf(ang, &sv, &cv);
            rc[i] = make_float2(cv, sv);
        }
    }

    const float* in = (tensor == 0) ? q : (tensor == 1) ? k : v;

    {
        int tl = tid >> 2, ec = (tid & 3) * 16;
        const float* src = in + ((size_t)b * 2048 + t0 + tl) * 512 + h * 64 + ec;
        #pragma unroll
        for (int m = 0; m < 4; m++) {
            float4 v4 = *(const float4*)(src + m * 4);
            Ts[tl][ec + m * 4 + 0] = v4.x;
            Ts[tl][ec + m * 4 + 1] = v4.y;
            Ts[tl][ec + m * 4 + 2] = v4.z;
            Ts[tl][ec + m * 4 + 3] = v4.w;
        }
    }
    __syncthreads();
    {
        int el = tid >> 2, tc = (tid & 3) * 16;
        size_t row = ((size_t)(tensor * 32 + b * 8 + h)) * 64 + el;
        unsigned short* dst = ttr + row * 2048 + t0 + tc;
        #pragma unroll
        for (int m = 0; m < 4; m++) {
            float a0 = Ts[tc + m * 4 + 0][el], a1 = Ts[tc + m * 4 + 1][el];
            float a2 = Ts[tc + m * 4 + 2][el], a3 = Ts[tc + m * 4 + 3][el];
            unsigned u0, u1;
            CVTPK(u0, a0, a1);
            CVTPK(u1, a2, a3);
            uint2 o; o.x = u0; o.y = u1;
            *(uint2*)(dst + m * 4) = o;
        }
    }
}

// ---------------------------------------------------------------------------
// Forward rFFT (ortho) via real-packing, 2 series per block.
// Output bf16 planes P[bh*128+kk][1056]; Q plane carries 0.125*log2e.
// V plane: 8-elem chunks stored at chunk ^ ((row>>2)&3) for conflict-free
// flash PV reads.  Series s = 2*blockIdx.x + b2; p = s%96; e = s/96.
// ---------------------------------------------------------------------------
__global__ __launch_bounds__(256) void fft_fwd(const unsigned short* __restrict__ ttr,
                                               const float2* __restrict__ twg,
                                               const float2* __restrict__ rc,
                                               unsigned short* __restrict__ Pq,
                                               unsigned short* __restrict__ Pk,
                                               unsigned short* __restrict__ Pv)
{
    __shared__ float2 buf[2][MMP];
    __shared__ float2 tw[TWP];

    int g   = blockIdx.x;             // 0..3071
    int tid = threadIdx.x;

    float scl[2];
    int vk3[2];
    unsigned short* dre[2];
    unsigned short* dim_[2];
    const unsigned short* src[2];
    #pragma unroll
    for (int b2 = 0; b2 < 2; b2++) {
        int s      = 2 * g + b2;
        int p      = s % 96;          // tensor*32 + bh
        int e      = s / 96;          // 0..63
        int tensor = p / 32;
        int bh     = p % 32;
        unsigned short* plane = (tensor == 0) ? Pq : (tensor == 1) ? Pk : Pv;
        scl[b2] = (tensor == 0) ? (INV_SQRT_N * 0.125f * LOG2E) : INV_SQRT_N;
        vk3[b2] = (tensor == 2) ? (((e >> 2) & 3) << 3) : 0;
        dre[b2] = plane + ((size_t)bh * 128 + e) * NYP;
        dim_[b2] = dre[b2] + (size_t)64 * NYP;
        src[b2] = ttr + ((size_t)p * 64 + e) * 2048;
    }

    #pragma unroll
    for (int i = tid; i < 768; i += 256) tw[PAD(i)] = twg[i];

    #pragma unroll
    for (int i = 0; i < 4; i++) {
        int j = tid + 256 * i;
        int d = PAD(dr4_10((unsigned)j));
        #pragma unroll
        for (int b2 = 0; b2 < 2; b2++) {
            unsigned pr = *(const unsigned*)(src[b2] + 2 * j);   // x[2j], x[2j+1]
            float x0 = bf2f((unsigned short)(pr & 0xFFFFu));
            float x1 = bf2f((unsigned short)(pr >> 16));
            buf[b2][d] = make_float2(x0, x1);
        }
    }
    __syncthreads();

    fft_r4_1024x2<true>(buf, tw, tid);

    // fwd combine uses (cs,sn) = (rc.x, -rc.y):
    //   XR = Ex + cx*Ox + cy*Oy ;  XI = Ey + cx*Oy - cy*Ox
#define RPOINT(Ai, Bi, CX, CY, SCL, XR, XI) do {                           \
        float Ex = 0.5f * (Ai.x + Bi.x), Ey = 0.5f * (Ai.y - Bi.y);        \
        float Dx = 0.5f * (Ai.x - Bi.x), Dy = 0.5f * (Ai.y + Bi.y);        \
        float Ox = Dy, Oy = -Dx;                                           \
        XR = (Ex + (CX) * Ox + (CY) * Oy) * (SCL);                         \
        XI = (Ey + (CX) * Oy - (CY) * Ox) * (SCL);                         \
    } while (0)

    #pragma unroll
    for (int i = 0; i < 2; i++) {
        int kk = 2 * tid + 512 * i;                  // even, 0..1022
        int d0 = PAD(kk), d0c = PAD((MM - kk) & (MM - 1));
        int d1 = PAD(kk + 1), d1c = PAD(MM - kk - 1);
        float4 rq = *(const float4*)(&rc[kk]);       // (c0,s0,c1,s1)
        #pragma unroll
        for (int b2 = 0; b2 < 2; b2++) {
            float2 A0 = buf[b2][d0], B0 = buf[b2][d0c];
            float2 A1 = buf[b2][d1], B1 = buf[b2][d1c];
            float Xr0, Xi0, Xr1, Xi1;
            RPOINT(A0, B0, rq.x, rq.y, scl[b2], Xr0, Xi0);
            RPOINT(A1, B1, rq.z, rq.w, scl[b2], Xr1, Xi1);
            unsigned ur, ui;
            CVTPK(ur, Xr0, Xr1);
            CVTPK(ui, Xi0, Xi1);
            int ks = kk ^ vk3[b2];                   // swizzle stays even
            *(unsigned*)(dre[b2] + ks)  = ur;
            *(unsigned*)(dim_[b2] + ks) = ui;
        }
    }
    // tail: kk = 1024 (cs=-1, sn=0) + zero pads 1025..1055, as u32 stores
    if (tid < 16) {
        #pragma unroll
        for (int b2 = 0; b2 < 2; b2++) {
            unsigned ur = 0, ui = 0;
            if (tid == 0) {
                float2 A = buf[b2][PAD(0)];           // A == Bc at kk=1024
                float Xr = (A.x - A.y) * scl[b2];     // Ex + (-1)*Ox
                float zz = 0.f;
                CVTPK(ur, Xr, zz);
            }
            int ks = (1024 + 2 * tid) ^ vk3[b2];
            *(unsigned*)(dre[b2] + ks)  = ur;
            *(unsigned*)(dim_[b2] + ks) = ui;
        }
    }
#undef RPOINT
}

// ---------------------------------------------------------------------------
// Transpose q,k planes [bh*128+kk][1056] -> [bh][1056][128].
// K rows are written with 16B chunks XOR-swizzled (chunk ^ (y&7)) so flash can
// DMA them linearly into LDS and still read bank-conflict-free (rule #21).
// ---------------------------------------------------------------------------
__global__ __launch_bounds__(256) void qkpack(const unsigned short* __restrict__ Pq,
                                              const unsigned short* __restrict__ Pk,
                                              unsigned short* __restrict__ Qp,
                                              unsigned short* __restrict__ Kp)
{
    __shared__ unsigned short Ts[32][136];
    int y0  = blockIdx.x * 32;
    int bh  = blockIdx.y;
    int tsr = blockIdx.z;
    int tid = threadIdx.x;

    const unsigned short* srcp = (tsr == 0) ? Pq : Pk;
    unsigned short* dstp       = (tsr == 0) ? Qp : Kp;

    {
        int kk = tid >> 1, seg = tid & 1;
        const unsigned short* sp = srcp + ((size_t)bh * 128 + kk) * NYP + y0 + seg * 16;
        uint4 va = *(const uint4*)sp;
        uint4 vb = *(const uint4*)(sp + 8);
        const unsigned short* pa = (const unsigned short*)&va;
        const unsigned short* pb = (const unsigned short*)&vb;
        #pragma unroll
        for (int j = 0; j < 8; j++) Ts[seg * 16 + j][kk] = pa[j];
        #pragma unroll
        for (int j = 0; j < 8; j++) Ts[seg * 16 + 8 + j][kk] = pb[j];
    }
    __syncthreads();
    {
        int y = tid >> 3, c = tid & 7;       // c: 32B pair (chunks 2c, 2c+1)
        uint4 lo = *(const uint4*)&Ts[y][c * 16];
        uint4 hi = *(const uint4*)&Ts[y][c * 16 + 8];
        char* rowb = (char*)(dstp + ((size_t)bh * NYP + y0 + y) * 128);
        if (tsr == 0) {
            *(uint4*)(rowb + c * 32)      = lo;
            *(uint4*)(rowb + c * 32 + 16) = hi;
        } else {
            int s = y & 7;
            *(uint4*)(rowb + (((2 * c)     ^ s) << 4)) = lo;
            *(uint4*)(rowb + (((2 * c + 1) ^ s) << 4)) = hi;
        }
    }
}

// ---------------------------------------------------------------------------
// MFMA flash attention, no-max softmax, y-split xNH, XCD swizzle.
// K/V staged via global_load_lds into LDS double-buffer; counted vmcnt(4)
// keeps next-tile loads in flight across raw s_barriers (T3/T4); setprio (T5).
// numb partial planes: [h][bh][kk=0..127][x=0..1055] bf16; planes 0,1 at nb0,
// planes 2,3 at nb1 (two disjoint ws regions).
// ---------------------------------------------------------------------------
struct FlashShared {
    union {
        struct {
            unsigned short Ks[2][32][128];   // 16 KB, chunk-XOR-swizzled rows
            unsigned short Vs[2][128][32];   // 16 KB, chunk-swizzled (fft_fwd)
        } kv;                                // 32 KB
        unsigned short OutT[128][72];        // 18 KB (epilogue only)
    } u;
    unsigned short Ps[4][16][40];            // 5 KB, wave-private
};

template<int NH>
__global__ __launch_bounds__(256) void flash_mfma(
    const unsigned short* __restrict__ Qp,   // [bh][1056][128] bf16 (scaled)
    const unsigned short* __restrict__ Kp,   // [bh][1056][128] bf16, swizzled
    const unsigned short* __restrict__ Vt,   // [bh*128+kk][1056] bf16, swizzled
    unsigned short* __restrict__ nb0,        // partial planes 0,1
    unsigned short* __restrict__ nb1,        // partial planes 2,3 (NH=4)
    float* __restrict__ lbuf)                // [NH][bh*1056+x] fp32
{
    __shared__ FlashShared S;

    int g    = blockIdx.x;            // idx*32 + bh : g%8 == bh%8 (XCD pin)
    int bh   = g & 31;
    int idx  = g >> 5;                // 0..17*NH-1
    int half = idx / 17;              // y-quarter (or y-half)
    int x0   = (idx % 17) * 64;
    int tid  = threadIdx.x;
    int w    = tid >> 6;
    int lane = tid & 63;
    int qd   = lane >> 4;
    int col  = lane & 15;

    // ---- Q A-fragments: direct bf16 loads + sign trick ----
    int xrow = x0 + w * 16 + col;
    int xq   = min(xrow, 1024);
    const unsigned short* qb = Qp + ((size_t)bh * NYP + xq) * 128 + qd * 8;
    bhalf8 Are[4], Aim[4];
    #pragma unroll
    for (int ks = 0; ks < 4; ks++) Are[ks] = *(const bhalf8*)(qb + ks * 32);
    Aim[0] = Are[2];                       // k<64 : Qi
    Aim[1] = Are[3];
    #pragma unroll
    for (int ks = 0; ks < 2; ks++) {       // k>=64: -Qr
        bhalf8 t = Are[ks];
        unsigned* u = (unsigned*)&t;
        #pragma unroll
        for (int j = 0; j < 4; j++) u[j] ^= 0x80008000u;
        Aim[ks + 2] = t;
    }

    f32x4 O[8];
    #pragma unroll
    for (int n = 0; n < 8; n++) O[n] = (f32x4){0.f, 0.f, 0.f, 0.f};
    float Lacc[4] = {0.f, 0.f, 0.f, 0.f};

    int yt0 = (half * 33) / NH, yt1 = ((half + 1) * 33) / NH;

    // ---- per-wave DMA source pointers (bytes) ----
    const char* ksrc = (const char*)Kp
        + ((size_t)bh * NYP + (size_t)yt0 * 32 + w * 8) * 256 + lane * 16;
    const char* vbase = (const char*)Vt + (size_t)bh * 128 * (NYP * 2);
    const char* vsrc0 = vbase + ((size_t)(w * 32) + (lane >> 2)) * (NYP * 2)
                        + (size_t)yt0 * 64 + (lane & 3) * 16;
    const char* vsrc1 = vsrc0 + (size_t)16 * (NYP * 2);

    // swizzled K chunk offsets (ushort units), loop-invariant per lane
    int sw = col & 7;
    int kco[4];
    #pragma unroll
    for (int ks = 0; ks < 4; ks++) kco[ks] = ((ks * 4 + qd) ^ sw) * 8;
    // V chunk unswizzle: stored position of chunk qd in row (n*16+col)
    int vq = (qd ^ ((col >> 2) & 3)) * 8;

    // ---- prologue: stage tile yt0 ----
    {
        int pb = yt0 & 1;
        GLD16(ksrc,         &S.u.kv.Ks[pb][w * 8][0]);
        GLD16(ksrc + 1024,  &S.u.kv.Ks[pb][w * 8 + 4][0]);
        GLD16(vsrc0,        &S.u.kv.Vs[pb][w * 32][0]);
        GLD16(vsrc1,        &S.u.kv.Vs[pb][w * 32 + 16][0]);
        ksrc += 8192; vsrc0 += 64; vsrc1 += 64;
    }

    for (int yt = yt0; yt < yt1; yt++) {
        int cb = yt & 1, nb = cb ^ 1;
        if (yt + 1 < yt1) {
            // issue next tile's DMA (stays in flight across both barriers)
            GLD16(ksrc,         &S.u.kv.Ks[nb][w * 8][0]);
            GLD16(ksrc + 1024,  &S.u.kv.Ks[nb][w * 8 + 4][0]);
            GLD16(vsrc0,        &S.u.kv.Vs[nb][w * 32][0]);
            GLD16(vsrc1,        &S.u.kv.Vs[nb][w * 32 + 16][0]);
            ksrc += 8192; vsrc0 += 64; vsrc1 += 64;
            __builtin_amdgcn_sched_barrier(0);
            asm volatile("s_waitcnt vmcnt(4)" ::: "memory");   // cur tile done
        } else {
            __builtin_amdgcn_sched_barrier(0);
            asm volatile("s_waitcnt vmcnt(0)" ::: "memory");
        }
        __builtin_amdgcn_sched_barrier(0);
        __builtin_amdgcn_s_barrier();                          // all waves' DMA visible
        __builtin_amdgcn_sched_barrier(0);

        const unsigned short* k0 = &S.u.kv.Ks[cb][col][0];
        const unsigned short* k1 = &S.u.kv.Ks[cb][col + 16][0];

        // ---- QK ----
        f32x4 sre[2], sim[2];
        #pragma unroll
        for (int sc = 0; sc < 2; sc++) {
            sre[sc] = (f32x4){0.f, 0.f, 0.f, 0.f};
            sim[sc] = (f32x4){0.f, 0.f, 0.f, 0.f};
        }
        __builtin_amdgcn_s_setprio(1);
        #pragma unroll
        for (int ks = 0; ks < 4; ks++) {
            bhalf8 b0 = *(const bhalf8*)(k0 + kco[ks]);
            bhalf8 b1 = *(const bhalf8*)(k1 + kco[ks]);
            sre[0] = MFMA16(Are[ks], b0, sre[0]);
            sim[0] = MFMA16(Aim[ks], b0, sim[0]);
            sre[1] = MFMA16(Are[ks], b1, sre[1]);
            sim[1] = MFMA16(Aim[ks], b1, sim[1]);
        }
        __builtin_amdgcn_s_setprio(0);

        // ---- p = exp2(sqrt(re^2+im^2))  (0.125*log2e folded into Q) ----
        #pragma unroll
        for (int r = 0; r < 4; r++) {
            float re0 = sre[0][r], im0 = sim[0][r];
            float re1 = sre[1][r], im1 = sim[1][r];
            float s0 = __builtin_amdgcn_sqrtf(fmaf(re0, re0, im0 * im0));
            float s1 = __builtin_amdgcn_sqrtf(fmaf(re1, re1, im1 * im1));
            float p0, p1;
            EXP2F(p0, s0);
            EXP2F(p1, s1);
            Lacc[r] += p0 + p1;
            unsigned up;
            CVTPK(up, p0, p1);
            S.Ps[w][qd * 4 + r][col]      = (unsigned short)up;
            S.Ps[w][qd * 4 + r][col + 16] = (unsigned short)(up >> 16);
        }

        // ---- PV ----
        bhalf8 pa = *(const bhalf8*)&S.Ps[w][col][qd * 8];
        __builtin_amdgcn_s_setprio(1);
        #pragma unroll
        for (int n = 0; n < 8; n++) {
            bhalf8 bv = *(const bhalf8*)&S.u.kv.Vs[cb][n * 16 + col][vq];
            O[n] = MFMA16(pa, bv, O[n]);
        }
        __builtin_amdgcn_s_setprio(0);

        asm volatile("s_waitcnt lgkmcnt(0)" ::: "memory");     // reads retired
        __builtin_amdgcn_sched_barrier(0);
        __builtin_amdgcn_s_barrier();                          // safe to overwrite cb^1
        __builtin_amdgcn_sched_barrier(0);
    }

    // ---- l reduce + store ----
    #pragma unroll
    for (int r = 0; r < 4; r++) {
        float ls = Lacc[r];
        ls += __shfl_xor(ls, 1);
        ls += __shfl_xor(ls, 2);
        ls += __shfl_xor(ls, 4);
        ls += __shfl_xor(ls, 8);
        if (yt1 == 33) ls -= 31.0f;        // zero-pad columns contributed 1 each
        int x = x0 + w * 16 + qd * 4 + r;
        if (x <= 1024 && col == 0)
            lbuf[((size_t)half * 32 + bh) * NYP + x] = ls;
    }

    // ---- numerator: C-layout -> LDS overlay -> coalesced row writes ----
    const size_t HSZ = (size_t)32 * 128 * NYP;
    unsigned short* nplane = (half < 2 ? nb0 : nb1) + (size_t)(half & 1) * HSZ;

    __syncthreads();                       // Ks/Vs dead; safe to overlay
    #pragma unroll
    for (int n = 0; n < 8; n++) {
        unsigned u0, u1;
        CVTPK(u0, O[n][0], O[n][1]);
        CVTPK(u1, O[n][2], O[n][3]);
        *(unsigned*)&S.u.OutT[n * 16 + col][w * 16 + qd * 4]     = u0;
        *(unsigned*)&S.u.OutT[n * 16 + col][w * 16 + qd * 4 + 2] = u1;
    }
    __syncthreads();
    {
        int kk2 = tid >> 1, seg = tid & 1;
        int xg  = x0 + seg * 32;
        if (xg < NYP) {
            unsigned short* dst = nplane + ((size_t)bh * 128 + kk2) * NYP + xg;
            const unsigned short* srcl = &S.u.OutT[kk2][seg * 32];
            #pragma unroll
            for (int m = 0; m < 4; m++)
                *(uint4*)(dst + m * 8) = *(const uint4*)(srcl + m * 8);
        }
    }
}

// ---------------------------------------------------------------------------
// Inverse rFFT (ortho): combine NH partial planes, 2 series (e, e+1) per
// block — shared l-denominators; packed padded radix-4 irFFT; write
// contiguous staging st[bh*64+e][2048] fp32.
// ---------------------------------------------------------------------------
template<int NH>
__global__ __launch_bounds__(256) void fft_inv(const unsigned short* __restrict__ nb0,
                                               const unsigned short* __restrict__ nb1,
                                               const float2* __restrict__ twg,
                                               const float2* __restrict__ rc,
                                               const float* __restrict__ lbuf,
                                               float* __restrict__ st)
{
    __shared__ float2 buf[2][MMP];
    __shared__ float2 tw[TWP];

    int g   = blockIdx.x;          // 0..1023 ; series 2g, 2g+1 share bh
    int e   = (2 * g) & 63;        // even
    int bh  = (2 * g) >> 6;
    int tid = threadIdx.x;

    #pragma unroll
    for (int i = tid; i < 768; i += 256) tw[PAD(i)] = twg[i];

    const size_t HSZ = (size_t)32 * 128 * NYP;
    const unsigned short* pre[NH];
    const unsigned short* pim[NH];
    const float* lb[NH];
    #pragma unroll
    for (int h = 0; h < NH; h++) {
        const unsigned short* base = (h < 2 ? nb0 : nb1) + (size_t)(h & 1) * HSZ;
        pre[h] = base + ((size_t)bh * 128 + e) * NYP;
        pim[h] = base + ((size_t)bh * 128 + 64 + e) * NYP;
        lb[h]  = lbuf + ((size_t)h * 32 + bh) * NYP;
    }

    #pragma unroll
    for (int i = 0; i < 4; i++) {
        int kk = tid + 256 * i;
        int x1 = kk, x2 = 1024 - kk;
        float d1 = 0.f, d2 = 0.f;
        #pragma unroll
        for (int h = 0; h < NH; h++) {
            d1 += lb[h][x1];
            d2 += lb[h][x2];
        }
        float iv1 = 1.f / d1, iv2 = 1.f / d2;     // shared by both series
        float2 rcv = rc[kk];                       // (cos, sin) of +2pi*kk/2048
        int dd = PAD(dr4_10((unsigned)kk));
        #pragma unroll
        for (int b2 = 0; b2 < 2; b2++) {
            int off = b2 * NYP;
            float Axs = 0.f, Ays = 0.f, Bxs = 0.f, Bys = 0.f;
            #pragma unroll
            for (int h = 0; h < NH; h++) {
                Axs += bf2f(pre[h][off + x1]);
                Ays += bf2f(pim[h][off + x1]);
                Bxs += bf2f(pre[h][off + x2]);
                Bys += bf2f(pim[h][off + x2]);
            }
            float Ax = Axs * iv1, Ay = Ays * iv1;
            float Bx = Bxs * iv2, By = -(Bys * iv2);
            float Ex = 0.5f * (Ax + Bx), Ey = 0.5f * (Ay + By);
            float Dx = 0.5f * (Ax - Bx), Dy = 0.5f * (Ay - By);
            float Ox = Dx * rcv.x - Dy * rcv.y;
            float Oy = Dx * rcv.y + Dy * rcv.x;
            buf[b2][dd] = make_float2(Ex - Oy, Ey + Ox);
        }
    }
    __syncthreads();

    fft_r4_1024x2<false>(buf, tw, tid);

    float* dst = st + ((size_t)bh * 64 + e) * 2048;
    #pragma unroll
    for (int i = 0; i < 4; i++) {
        int j = tid + 256 * i;
        int dj = PAD(j);
        float2 z0 = buf[0][dj];
        float2 z1 = buf[1][dj];
        *(float2*)&dst[2 * j] = make_float2(z0.x * INV_SCALE, z0.y * INV_SCALE);
        *(float2*)&dst[2048 + 2 * j] = make_float2(z1.x * INV_SCALE, z1.y * INV_SCALE);
    }
}

// ---------------------------------------------------------------------------
// Final transpose: st[bh*64+e][t] -> out[b][t][h][e].  64x64 tiles via LDS.
// ---------------------------------------------------------------------------
__global__ __launch_bounds__(256) void out_tr(const float* __restrict__ st,
                                              float* __restrict__ out)
{
    __shared__ float Ts[64][65];
    int tt  = blockIdx.x;         // t-tile 0..31
    int h   = blockIdx.y;         // 0..7
    int b   = blockIdx.z;         // 0..3
    int tid = threadIdx.x;
    int bh  = b * 8 + h;

    {
        int e = tid >> 2, tc = (tid & 3) * 16;
        const float* src = st + ((size_t)bh * 64 + e) * 2048 + tt * 64 + tc;
        #pragma unroll
        for (int m = 0; m < 4; m++) {
            float4 v4 = *(const float4*)(src + m * 4);
            Ts[e][tc + m * 4 + 0] = v4.x;
            Ts[e][tc + m * 4 + 1] = v4.y;
            Ts[e][tc + m * 4 + 2] = v4.z;
            Ts[e][tc + m * 4 + 3] = v4.w;
        }
    }
    __syncthreads();
    {
        int t = tid >> 2, ec = (tid & 3) * 16;
        float* dst = out + (size_t)b * 2048 * 512 + (size_t)(tt * 64 + t) * 512
                     + h * 64 + ec;
        #pragma unroll
        for (int m = 0; m < 4; m++) {
            float4 v4;
            v4.x = Ts[ec + m * 4 + 0][t];
            v4.y = Ts[ec + m * 4 + 1][t];
            v4.z = Ts[ec + m * 4 + 2][t];
            v4.w = Ts[ec + m * 4 + 3][t];
            *(float4*)(dst + m * 4) = v4;
        }
    }
}

// ---------------------------------------------------------------------------
extern "C" void kernel_launch(void* const* d_in, const int* in_sizes, int n_in,
                              void* d_out, int out_size, void* d_ws, size_t ws_size,
                              hipStream_t stream)
{
    const float* q = (const float*)d_in[0];
    const float* k = (const float*)d_in[1];
    const float* v = (const float*)d_in[2];
    float* out = (float*)d_out;

    char* ws = (char*)d_ws;
    const size_t PL = (size_t)32 * 128 * NYP * sizeof(unsigned short); // 8.65 MB
    unsigned short* Pq = (unsigned short*)(ws);
    unsigned short* Pk = (unsigned short*)(ws + PL);
    unsigned short* Pv = (unsigned short*)(ws + 2 * PL);
    // ttr at 3PL (25.2 MB); dead after fft_fwd, then Qp/Kp reuse the space.
    unsigned short* ttr = (unsigned short*)(ws + 3 * PL);
    unsigned short* Qp = (unsigned short*)(ws + 3 * PL);
    unsigned short* Kp = (unsigned short*)(ws + 4 * PL);
    // st aliases Qp+Kp (dead after flash_mfma): 16.78 MB; ends before 5PL.
    float* st = (float*)(ws + 3 * PL);

    const size_t lbuf4 = (size_t)4 * 32 * NYP * sizeof(float);
    const size_t lbuf2 = (size_t)2 * 32 * NYP * sizeof(float);
    const size_t TBL   = (size_t)(768 + 768 + 1025) * sizeof(float2);  // 20.5 KB
    bool big = ws_size >= 7 * PL + lbuf4 + TBL;

    // tables live past every live region in both paths
    char* tb = big ? (ws + 7 * PL + lbuf4) : (ws + 5 * PL + lbuf2);
    float2* twf = (float2*)tb;
    float2* twi = twf + 768;
    float2* rc  = twi + 768;

    hipLaunchKernelGGL(tr_fwd, dim3(32, 8, 12), dim3(256), 0, stream,
                       q, k, v, ttr, twf, twi, rc);
    hipLaunchKernelGGL(fft_fwd, dim3(3 * 1024), dim3(256), 0, stream,
                       ttr, twf, rc, Pq, Pk, Pv);
    hipLaunchKernelGGL(qkpack, dim3(33, 32, 2), dim3(256), 0, stream,
                       Pq, Pk, Qp, Kp);

    if (big) {
        unsigned short* nb0 = (unsigned short*)(ws);
        unsigned short* nb1 = (unsigned short*)(ws + 5 * PL);
        float* lbuf = (float*)(ws + 7 * PL);
        hipLaunchKernelGGL((flash_mfma<4>), dim3(17 * 4 * 32), dim3(256), 0, stream,
                           Qp, Kp, Pv, nb0, nb1, lbuf);
        hipLaunchKernelGGL((fft_inv<4>), dim3(1024), dim3(256), 0, stream,
                           nb0, nb1, twi, rc, lbuf, st);
    } else {
        unsigned short* nb0 = (unsigned short*)(ws);
        float* lbuf = (float*)(ws + 5 * PL);
        hipLaunchKernelGGL((flash_mfma<2>), dim3(17 * 2 * 32), dim3(256), 0, stream,
                           Qp, Kp, Pv, nb0, nb0, lbuf);
        hipLaunchKernelGGL((fft_inv<2>), dim3(1024), dim3(256), 0, stream,
                           nb0, nb0, twi, rc, lbuf, st);
    }

    hipLaunchKernelGGL(out_tr, dim3(32, 8, 4), dim3(256), 0, stream,
                       st, out);
}